// Round 1
// baseline (1992.724 us; speedup 1.0000x reference)
//
#include <hip/hip_runtime.h>
#include <hip/hip_bf16.h>

typedef unsigned short u16;
typedef __attribute__((ext_vector_type(4))) float f32x4;
typedef __attribute__((ext_vector_type(8))) short bf16x8;
typedef __attribute__((ext_vector_type(8))) unsigned short u16x8;
typedef __attribute__((ext_vector_type(4))) unsigned short u16x4;

#define BM 128
#define BN 128
#define BK 64

__device__ __forceinline__ u16 f2bf(float f) {
  union { float f; unsigned u; } v; v.f = f;
  unsigned r = v.u + 0x7FFFu + ((v.u >> 16) & 1u);
  return (u16)(r >> 16);
}

// ---------------------------------------------------------------- GEMM core
// A: [*,K] bf16 row-major (already offset to tile row 0), lda in elements
// Bt: [*,K] bf16 row-major (B transposed; offset to tile col 0), ldb elements
// Computes 128x128 tile, 256 threads (4 waves, each 64x64).
__device__ __forceinline__ void gemm_core(
    const u16* __restrict__ A, int lda,
    const u16* __restrict__ Bt, int ldb,
    int ksteps, u16* sA, u16* sB, f32x4 acc[4][4]) {
  const int tid = threadIdx.x;
  const int wave = tid >> 6;
  const int lane = tid & 63;
  const int r = tid >> 3;        // row within tile for staging (base, +32 per iter)
  const int ks = tid & 7;        // 16B segment within row
  const int wm = (wave >> 1) * 64;
  const int wn = (wave & 1) * 64;
  const int lr = lane & 15;
  const int lk = (lane >> 4) * 8;

  for (int kt = 0; kt < ksteps; ++kt) {
    const int k0 = kt * BK;
#pragma unroll
    for (int i = 0; i < 4; ++i) {
      // unit index = i*256 + tid ; row = unit>>3 = i*32 + r ; seg = ks
      __builtin_amdgcn_global_load_lds(
          (const __attribute__((address_space(1))) void*)(A + (size_t)(i * 32 + r) * lda + k0 + ks * 8),
          (__attribute__((address_space(3))) void*)(sA + i * 2048 + wave * 512),
          16, 0, 0);
      __builtin_amdgcn_global_load_lds(
          (const __attribute__((address_space(1))) void*)(Bt + (size_t)(i * 32 + r) * ldb + k0 + ks * 8),
          (__attribute__((address_space(3))) void*)(sB + i * 2048 + wave * 512),
          16, 0, 0);
    }
    __syncthreads();
#pragma unroll
    for (int kk = 0; kk < BK; kk += 32) {
      bf16x8 av[4], bv[4];
#pragma unroll
      for (int m = 0; m < 4; ++m)
        av[m] = *(const bf16x8*)&sA[(wm + m * 16 + lr) * BK + kk + lk];
#pragma unroll
      for (int n = 0; n < 4; ++n)
        bv[n] = *(const bf16x8*)&sB[(wn + n * 16 + lr) * BK + kk + lk];
#pragma unroll
      for (int m = 0; m < 4; ++m)
#pragma unroll
        for (int n = 0; n < 4; ++n)
          acc[m][n] = __builtin_amdgcn_mfma_f32_16x16x32_bf16(av[m], bv[n], acc[m][n], 0, 0, 0);
    }
    __syncthreads();
  }
}

__device__ __forceinline__ void acc_zero(f32x4 acc[4][4]) {
#pragma unroll
  for (int m = 0; m < 4; ++m)
#pragma unroll
    for (int n = 0; n < 4; ++n)
      acc[m][n] = (f32x4){0.f, 0.f, 0.f, 0.f};
}

// ------------------------------------------------------------- QKV GEMM
// x[2048,2048]bf16 @ Wqkv^T[4096,2048]bf16 -> scatter Q[b,h,s,d], K[b,kv,s,d], VT[b,kv,d,s] (bf16)
__global__ __launch_bounds__(256) void k_gemm_qkv(
    const u16* __restrict__ A, const u16* __restrict__ Bt,
    u16* __restrict__ Q, u16* __restrict__ Kb, u16* __restrict__ VT) {
  const int tm = blockIdx.x >> 5;
  const int tn = blockIdx.x & 31;
  __shared__ u16 sA[BM * BK], sB[BN * BK];
  f32x4 acc[4][4];
  acc_zero(acc);
  gemm_core(A + (size_t)tm * 128 * 2048, 2048, Bt + (size_t)tn * 128 * 2048, 2048, 32, sA, sB, acc);
  const int lane = threadIdx.x & 63, wave = threadIdx.x >> 6;
  const int wm = (wave >> 1) * 64, wn = (wave & 1) * 64;
  const int col = lane & 15, rb = (lane >> 4) * 4;
#pragma unroll
  for (int m = 0; m < 4; ++m)
#pragma unroll
    for (int n = 0; n < 4; ++n)
#pragma unroll
      for (int j = 0; j < 4; ++j) {
        int gm = tm * 128 + wm + m * 16 + rb + j;
        int gn = tn * 128 + wn + n * 16 + col;
        u16 bvv = f2bf(acc[m][n][j]);
        int b = gm >> 10, s = gm & 1023;
        if (gn < 2048) {
          int hh = gn >> 7, d = gn & 127;
          Q[(size_t)(((b * 16 + hh) << 10) + s) * 128 + d] = bvv;
        } else if (gn < 3072) {
          int kv = (gn - 2048) >> 7, d = gn & 127;
          Kb[(size_t)(((b * 8 + kv) << 10) + s) * 128 + d] = bvv;
        } else {
          int kv = (gn - 3072) >> 7, d = gn & 127;
          VT[(size_t)(((b * 8 + kv) << 7) + d) * 1024 + s] = bvv;
        }
      }
}

// ------------------------------------------------------------- generic GEMM + epilogue
// mode: 0 = Cf += C ; 1 = Cb = bf16(silu(C)) ; 2 = Cf += (mask[row]==want ? C : 0)
__global__ __launch_bounds__(256) void k_gemm_epi(
    const u16* __restrict__ A, int lda, const u16* __restrict__ Bt, int ldb,
    int ksteps, int ntn, float* __restrict__ Cf, u16* __restrict__ Cb, int ldc,
    int mode, const int* __restrict__ mask, int want) {
  const int tm = blockIdx.x / ntn;
  const int tn = blockIdx.x % ntn;
  __shared__ u16 sA[BM * BK], sB[BN * BK];
  f32x4 acc[4][4];
  acc_zero(acc);
  gemm_core(A + (size_t)tm * 128 * lda, lda, Bt + (size_t)tn * 128 * ldb, ldb, ksteps, sA, sB, acc);
  const int lane = threadIdx.x & 63, wave = threadIdx.x >> 6;
  const int wm = (wave >> 1) * 64, wn = (wave & 1) * 64;
  const int col = lane & 15, rb = (lane >> 4) * 4;
#pragma unroll
  for (int m = 0; m < 4; ++m)
#pragma unroll
    for (int n = 0; n < 4; ++n)
#pragma unroll
      for (int j = 0; j < 4; ++j) {
        int gm = tm * 128 + wm + m * 16 + rb + j;
        int gn = tn * 128 + wn + n * 16 + col;
        float v = acc[m][n][j];
        size_t idx = (size_t)gm * ldc + gn;
        if (mode == 0) {
          Cf[idx] += v;
        } else if (mode == 1) {
          float s = v / (1.f + __expf(-v));
          Cb[idx] = f2bf(s);
        } else {
          if (mask[gm] == want) Cf[idx] += v;
        }
      }
}

// ------------------------------------------------------------- scores (causal tiles)
__global__ __launch_bounds__(256) void k_scores(
    const u16* __restrict__ Q, const u16* __restrict__ Kb, float* __restrict__ S, int bh0) {
  const int zz = blockIdx.y;
  const int bh = bh0 + zz;
  const int b = bh >> 4, hq = bh & 15, kv = hq >> 1;
  int i = blockIdx.x;
  int tm = 0;
  while ((tm + 1) * (tm + 2) / 2 <= i) ++tm;
  int tn = i - tm * (tm + 1) / 2;
  __shared__ u16 sA[BM * BK], sB[BN * BK];
  f32x4 acc[4][4];
  acc_zero(acc);
  const u16* Aq = Q + ((size_t)(b * 16 + hq) * 1024 + tm * 128) * 128;
  const u16* Bk = Kb + ((size_t)(b * 8 + kv) * 1024 + tn * 128) * 128;
  gemm_core(Aq, 128, Bk, 128, 2, sA, sB, acc);
  float* Sb = S + ((size_t)zz << 20);
  const int lane = threadIdx.x & 63, wave = threadIdx.x >> 6;
  const int wm = (wave >> 1) * 64, wn = (wave & 1) * 64;
  const int col = lane & 15, rb = (lane >> 4) * 4;
#pragma unroll
  for (int m = 0; m < 4; ++m)
#pragma unroll
    for (int n = 0; n < 4; ++n)
#pragma unroll
      for (int j = 0; j < 4; ++j)
        Sb[(size_t)(tm * 128 + wm + m * 16 + rb + j) * 1024 + tn * 128 + wn + n * 16 + col] =
            acc[m][n][j];
}

// ------------------------------------------------------------- row softmax -> bf16 P
__global__ __launch_bounds__(256) void k_softmax(const float* __restrict__ S, u16* __restrict__ P) {
  const int q = blockIdx.x;
  const int zz = blockIdx.y;
  const int tid = threadIdx.x;
  const float* row = S + ((size_t)zz << 20) + ((size_t)q << 10);
  u16* prow = P + ((size_t)zz << 20) + ((size_t)q << 10);
  const float scale = 0.08838834764831845f;
  float4 v = ((const float4*)row)[tid];
  const float* vf = (const float*)&v;
  float vals[4];
  float mx = -3.0e38f;
#pragma unroll
  for (int j = 0; j < 4; ++j) {
    int colj = tid * 4 + j;
    float t = (colj <= q) ? vf[j] * scale : -3.0e38f;
    vals[j] = t;
    mx = fmaxf(mx, t);
  }
  __shared__ float red[8];
#pragma unroll
  for (int o = 32; o; o >>= 1) mx = fmaxf(mx, __shfl_xor(mx, o));
  if ((tid & 63) == 0) red[tid >> 6] = mx;
  __syncthreads();
  mx = fmaxf(fmaxf(red[0], red[1]), fmaxf(red[2], red[3]));
  float e[4];
  float sum = 0.f;
#pragma unroll
  for (int j = 0; j < 4; ++j) {
    int colj = tid * 4 + j;
    e[j] = (colj <= q) ? __expf(vals[j] - mx) : 0.f;
    sum += e[j];
  }
#pragma unroll
  for (int o = 32; o; o >>= 1) sum += __shfl_xor(sum, o);
  if ((tid & 63) == 0) red[4 + (tid >> 6)] = sum;
  __syncthreads();
  float inv = 1.f / (red[4] + red[5] + red[6] + red[7]);
  u16x4 ov;
#pragma unroll
  for (int j = 0; j < 4; ++j) ov[j] = f2bf(e[j] * inv);
  *(u16x4*)&prow[tid * 4] = ov;
}

// ------------------------------------------------------------- PV (causal K limit)
__global__ __launch_bounds__(256) void k_pv(
    const u16* __restrict__ P, const u16* __restrict__ VT, u16* __restrict__ O, int bh0) {
  const int zz = blockIdx.y;
  const int bh = bh0 + zz;
  const int b = bh >> 4, hq = bh & 15, kv = hq >> 1;
  const int tm = blockIdx.x;
  __shared__ u16 sA[BM * BK], sB[BN * BK];
  f32x4 acc[4][4];
  acc_zero(acc);
  const u16* Ap = P + ((size_t)zz << 20) + (size_t)tm * 128 * 1024;
  const u16* Bv = VT + (size_t)(b * 8 + kv) * 128 * 1024;
  gemm_core(Ap, 1024, Bv, 1024, (tm + 1) * 2, sA, sB, acc);
  const int lane = threadIdx.x & 63, wave = threadIdx.x >> 6;
  const int wm = (wave >> 1) * 64, wn = (wave & 1) * 64;
  const int col = lane & 15, rb = (lane >> 4) * 4;
#pragma unroll
  for (int m = 0; m < 4; ++m)
#pragma unroll
    for (int n = 0; n < 4; ++n)
#pragma unroll
      for (int j = 0; j < 4; ++j) {
        int s = tm * 128 + wm + m * 16 + rb + j;
        int d = wn + n * 16 + col;
        O[(size_t)(b * 1024 + s) * 2048 + hq * 128 + d] = f2bf(acc[m][n][j]);
      }
}

// ------------------------------------------------------------- transpose+convert W[K,N]f32 -> Wt[N,K]bf16
__global__ __launch_bounds__(256) void k_transpose(
    const float* __restrict__ W, u16* __restrict__ Wt, int K, int N) {
  __shared__ float tile[64][65];
  const int nk = K >> 6;
  const int tk = blockIdx.x % nk;
  const int tn = blockIdx.x / nk;
  const int tid = threadIdx.x;
#pragma unroll
  for (int i = 0; i < 16; ++i) {
    int u = i * 256 + tid;
    int r = u >> 6, c = u & 63;
    tile[r][c] = W[(size_t)(tk * 64 + r) * N + tn * 64 + c];
  }
  __syncthreads();
#pragma unroll
  for (int i = 0; i < 16; ++i) {
    int u = i * 256 + tid;
    int r = u >> 6, c = u & 63;
    Wt[(size_t)(tn * 64 + r) * K + tk * 64 + c] = f2bf(tile[c][r]);
  }
}

// ------------------------------------------------------------- RMS norms
__device__ __forceinline__ float block_sum256(float v, float* red) {
  const int tid = threadIdx.x;
#pragma unroll
  for (int o = 32; o; o >>= 1) v += __shfl_xor(v, o);
  if ((tid & 63) == 0) red[tid >> 6] = v;
  __syncthreads();
  float r = red[0] + red[1] + red[2] + red[3];
  __syncthreads();
  return r;
}

// out2 != null: out1 = rms*wt, out2 = rms*wa (both dense)
// out2 == null: out1 = rms * (mask ? wa : wt)
__global__ __launch_bounds__(256) void k_rms(
    const float* __restrict__ h, const float* __restrict__ wt, const float* __restrict__ wa,
    const int* __restrict__ mask, u16* __restrict__ out1, u16* __restrict__ out2) {
  const int row = blockIdx.x;
  const int tid = threadIdx.x;
  const float* hr = h + (size_t)row * 2048;
  float4 v0 = ((const float4*)hr)[tid * 2];
  float4 v1 = ((const float4*)hr)[tid * 2 + 1];
  const float* f0 = (const float*)&v0;
  const float* f1 = (const float*)&v1;
  float ss = 0.f;
#pragma unroll
  for (int j = 0; j < 4; ++j) ss += f0[j] * f0[j] + f1[j] * f1[j];
  __shared__ float red[4];
  ss = block_sum256(ss, red);
  const float inv = rsqrtf(ss * (1.0f / 2048.0f) + 1e-5f);
  const int c0 = tid * 8;
  if (out2) {
    u16x8 a, bb;
#pragma unroll
    for (int j = 0; j < 8; ++j) {
      float hv = (j < 4 ? f0[j] : f1[j - 4]) * inv;
      a[j] = f2bf(hv * wt[c0 + j]);
      bb[j] = f2bf(hv * wa[c0 + j]);
    }
    *(u16x8*)&out1[(size_t)row * 2048 + c0] = a;
    *(u16x8*)&out2[(size_t)row * 2048 + c0] = bb;
  } else {
    const float* w = mask[row] ? wa : wt;
    u16x8 a;
#pragma unroll
    for (int j = 0; j < 8; ++j) {
      float hv = (j < 4 ? f0[j] : f1[j - 4]) * inv;
      a[j] = f2bf(hv * w[c0 + j]);
    }
    *(u16x8*)&out1[(size_t)row * 2048 + c0] = a;
  }
}

__global__ __launch_bounds__(256) void k_rms_final(
    const float* __restrict__ h, const float* __restrict__ w, float* __restrict__ out) {
  const int row = blockIdx.x;
  const int tid = threadIdx.x;
  const float* hr = h + (size_t)row * 2048;
  float4 v0 = ((const float4*)hr)[tid * 2];
  float4 v1 = ((const float4*)hr)[tid * 2 + 1];
  const float* f0 = (const float*)&v0;
  const float* f1 = (const float*)&v1;
  float ss = 0.f;
#pragma unroll
  for (int j = 0; j < 4; ++j) ss += f0[j] * f0[j] + f1[j] * f1[j];
  __shared__ float red[4];
  ss = block_sum256(ss, red);
  const float inv = rsqrtf(ss * (1.0f / 2048.0f) + 1e-5f);
  float4 o0, o1;
  float* p0 = (float*)&o0;
  float* p1 = (float*)&o1;
  const int c0 = tid * 8;
#pragma unroll
  for (int j = 0; j < 4; ++j) {
    p0[j] = f0[j] * inv * w[c0 + j];
    p1[j] = f1[j] * inv * w[c0 + 4 + j];
  }
  ((float4*)(out + (size_t)row * 2048))[tid * 2] = o0;
  ((float4*)(out + (size_t)row * 2048))[tid * 2 + 1] = o1;
}

// ------------------------------------------------------------- embedding
__global__ __launch_bounds__(256) void k_embed(
    const int* __restrict__ ids, const float* __restrict__ vocab,
    const float* __restrict__ audio, float* __restrict__ h, int* __restrict__ mask) {
  const int t = blockIdx.x;
  const int tid = threadIdx.x;
  const int id = ids[t];
  const int am = (id > 31999) ? 1 : 0;
  if (tid == 0) mask[t] = am;
  float* hr = h + (size_t)t * 2048;
  if (!am) {
    const float4* src = (const float4*)(vocab + (size_t)id * 2048);
    for (int j = tid; j < 512; j += 256) ((float4*)hr)[j] = src[j];
  } else {
    const int aid = id - 32000;
    for (int j = tid; j < 512; j += 256) {
      float4 s = {0.f, 0.f, 0.f, 0.f};
#pragma unroll
      for (int c = 0; c < 8; ++c) {
        float4 a = ((const float4*)(audio + (size_t)(aid + c * 1026) * 2048))[j];
        s.x += a.x; s.y += a.y; s.z += a.z; s.w += a.w;
      }
      ((float4*)hr)[j] = s;
    }
  }
}

// ------------------------------------------------------------- host launch
extern "C" void kernel_launch(void* const* d_in, const int* in_sizes, int n_in,
                              void* d_out, int out_size, void* d_ws, size_t ws_size,
                              hipStream_t stream) {
  const int* ids = (const int*)d_in[0];
  const float* vocab = (const float*)d_in[1];
  const float* audio = (const float*)d_in[2];
  const float* ln_in = (const float*)d_in[3];
  const float* ln_audio_in = (const float*)d_in[4];
  const float* ln_post = (const float*)d_in[5];
  const float* ln_audio_post = (const float*)d_in[6];
  const float* w_qkv = (const float*)d_in[7];
  const float* w_o = (const float*)d_in[8];
  const float* w_fc = (const float*)d_in[9];
  const float* w_proj = (const float*)d_in[10];
  const float* w_afc = (const float*)d_in[11];
  const float* w_aproj = (const float*)d_in[12];
  const float* ln_f = (const float*)d_in[13];
  float* out = (float*)d_out;

  char* p = (char*)d_ws;
  auto alloc = [&](size_t bytes) {
    char* r = p;
    p += (bytes + 255) & ~(size_t)255;
    return r;
  };
  float* h   = (float*)alloc((size_t)2048 * 2048 * 4);
  u16* x     = (u16*)alloc((size_t)2048 * 2048 * 2);
  u16* xa    = (u16*)alloc((size_t)2048 * 2048 * 2);
  u16* o     = (u16*)alloc((size_t)2048 * 2048 * 2);
  int* mask  = (int*)alloc((size_t)2048 * 4);
  u16* Wt    = (u16*)alloc((size_t)8192 * 2048 * 2);
  u16* Q     = (u16*)alloc((size_t)2 * 16 * 1024 * 128 * 2);
  u16* Kb    = (u16*)alloc((size_t)2 * 8 * 1024 * 128 * 2);
  u16* VT    = (u16*)alloc((size_t)2 * 8 * 1024 * 128 * 2);
  float* S   = (float*)alloc((size_t)8 * 1024 * 1024 * 4);
  u16* P     = (u16*)alloc((size_t)8 * 1024 * 1024 * 2);
  u16* t1    = (u16*)alloc((size_t)2048 * 8192 * 2);
  (void)ws_size; (void)in_sizes; (void)n_in; (void)out_size;

  k_embed<<<2048, 256, 0, stream>>>(ids, vocab, audio, h, mask);

  for (int l = 0; l < 2; ++l) {
    // input norm (row-masked select)
    k_rms<<<2048, 256, 0, stream>>>(h, ln_in + l * 2048, ln_audio_in + l * 2048, mask, x, nullptr);
    // qkv
    k_transpose<<<(2048 / 64) * (4096 / 64), 256, 0, stream>>>(w_qkv + (size_t)l * 2048 * 4096, Wt, 2048, 4096);
    k_gemm_qkv<<<16 * 32, 256, 0, stream>>>(x, Wt, Q, Kb, VT);
    // attention, 4 chunks of 8 (b,h)
    for (int c = 0; c < 4; ++c) {
      k_scores<<<dim3(36, 8), 256, 0, stream>>>(Q, Kb, S, c * 8);
      k_softmax<<<dim3(1024, 8), 256, 0, stream>>>(S, P);
      k_pv<<<dim3(8, 8), 256, 0, stream>>>(P, VT, o, c * 8);
    }
    // o-proj (+residual)
    k_transpose<<<(2048 / 64) * (2048 / 64), 256, 0, stream>>>(w_o + (size_t)l * 2048 * 2048, Wt, 2048, 2048);
    k_gemm_epi<<<16 * 16, 256, 0, stream>>>(o, 2048, Wt, 2048, 32, 16, h, nullptr, 2048, 0, nullptr, 0);
    // post norm (both paths)
    k_rms<<<2048, 256, 0, stream>>>(h, ln_post + l * 2048, ln_audio_post + l * 2048, mask, x, xa);
    // text FFN
    k_transpose<<<(2048 / 64) * (8192 / 64), 256, 0, stream>>>(w_fc + (size_t)l * 2048 * 8192, Wt, 2048, 8192);
    k_gemm_epi<<<16 * 64, 256, 0, stream>>>(x, 2048, Wt, 2048, 32, 64, nullptr, t1, 8192, 1, nullptr, 0);
    k_transpose<<<(8192 / 64) * (2048 / 64), 256, 0, stream>>>(w_proj + (size_t)l * 8192 * 2048, Wt, 8192, 2048);
    k_gemm_epi<<<16 * 16, 256, 0, stream>>>(t1, 8192, Wt, 8192, 128, 16, h, nullptr, 2048, 2, mask, 0);
    // audio FFN
    k_transpose<<<(2048 / 64) * (8192 / 64), 256, 0, stream>>>(w_afc + (size_t)l * 2048 * 8192, Wt, 2048, 8192);
    k_gemm_epi<<<16 * 64, 256, 0, stream>>>(xa, 2048, Wt, 2048, 32, 64, nullptr, t1, 8192, 1, nullptr, 0);
    k_transpose<<<(8192 / 64) * (2048 / 64), 256, 0, stream>>>(w_aproj + (size_t)l * 8192 * 2048, Wt, 8192, 2048);
    k_gemm_epi<<<16 * 16, 256, 0, stream>>>(t1, 8192, Wt, 8192, 128, 16, h, nullptr, 2048, 2, mask, 1);
  }

  k_rms_final<<<2048, 256, 0, stream>>>(h, ln_f, out);
}

// Round 2
// 1910.605 us; speedup vs baseline: 1.0430x; 1.0430x over previous
//
#include <hip/hip_runtime.h>
#include <hip/hip_bf16.h>

typedef unsigned short u16;
typedef __attribute__((ext_vector_type(4))) float f32x4;
typedef __attribute__((ext_vector_type(8))) short bf16x8;
typedef __attribute__((ext_vector_type(8))) unsigned short u16x8;
typedef __attribute__((ext_vector_type(4))) unsigned short u16x4;

#define BM 128
#define BN 128
#define BK 64

__device__ __forceinline__ u16 f2bf(float f) {
  union { float f; unsigned u; } v; v.f = f;
  unsigned r = v.u + 0x7FFFu + ((v.u >> 16) & 1u);
  return (u16)(r >> 16);
}

__device__ __forceinline__ void acc_zero(f32x4 acc[4][4]) {
#pragma unroll
  for (int m = 0; m < 4; ++m)
#pragma unroll
    for (int n = 0; n < 4; ++n)
      acc[m][n] = (f32x4){0.f, 0.f, 0.f, 0.f};
}

// ---------------------------------------------------------------- GEMM core
// Double-buffered "minimum 2-phase" (T3 recipe): STAGE(next) || compute(cur),
// one raw s_barrier + vmcnt(0) per K-step; prefetch loads stay in flight
// across the whole compute phase. LDS 2x(128x64) per operand = 64 KB.
// A rows are clamped to amax (for compacted-row GEMMs; pass huge for none).
__device__ __forceinline__ void gemm_core_db(
    const u16* __restrict__ A, int lda,
    const u16* __restrict__ Bt, int ldb,
    int ksteps, int amax, u16* sA, u16* sB, f32x4 acc[4][4]) {
  const int tid = threadIdx.x;
  const int wave = tid >> 6;
  const int lane = tid & 63;
  const int r = tid >> 3;        // staging row base (+32 per i)
  const int ks = tid & 7;        // 16B segment within row
  const int wm = (wave >> 1) * 64;
  const int wn = (wave & 1) * 64;
  const int lr = lane & 15;
  const int lk = (lane >> 4) * 8;

  auto stage = [&](int buf, int kt) {
    const int k0 = kt * BK;
    u16* dA = sA + buf * 8192 + wave * 512;
    u16* dB = sB + buf * 8192 + wave * 512;
#pragma unroll
    for (int i = 0; i < 4; ++i) {
      int ra = i * 32 + r; if (ra > amax) ra = amax;
      __builtin_amdgcn_global_load_lds(
          (const __attribute__((address_space(1))) void*)(A + (size_t)ra * lda + k0 + ks * 8),
          (__attribute__((address_space(3))) void*)(dA + i * 2048), 16, 0, 0);
      __builtin_amdgcn_global_load_lds(
          (const __attribute__((address_space(1))) void*)(Bt + (size_t)(i * 32 + r) * ldb + k0 + ks * 8),
          (__attribute__((address_space(3))) void*)(dB + i * 2048), 16, 0, 0);
    }
  };

  stage(0, 0);
  asm volatile("s_waitcnt vmcnt(0)" ::: "memory");
  __builtin_amdgcn_s_barrier();
  __builtin_amdgcn_sched_barrier(0);

  for (int kt = 0; kt < ksteps; ++kt) {
    const int cur = kt & 1;
    if (kt + 1 < ksteps) stage(cur ^ 1, kt + 1);
    const u16* cA = sA + cur * 8192;
    const u16* cB = sB + cur * 8192;
#pragma unroll
    for (int kk = 0; kk < BK; kk += 32) {
      bf16x8 av[4], bv[4];
#pragma unroll
      for (int m = 0; m < 4; ++m)
        av[m] = *(const bf16x8*)&cA[(wm + m * 16 + lr) * BK + kk + lk];
#pragma unroll
      for (int n = 0; n < 4; ++n)
        bv[n] = *(const bf16x8*)&cB[(wn + n * 16 + lr) * BK + kk + lk];
#pragma unroll
      for (int m = 0; m < 4; ++m)
#pragma unroll
        for (int n = 0; n < 4; ++n)
          acc[m][n] = __builtin_amdgcn_mfma_f32_16x16x32_bf16(av[m], bv[n], acc[m][n], 0, 0, 0);
    }
    asm volatile("s_waitcnt vmcnt(0)" ::: "memory");
    __builtin_amdgcn_s_barrier();
    __builtin_amdgcn_sched_barrier(0);
  }
}

// ------------------------------------------------------------- QKV GEMM
__global__ __launch_bounds__(256) void k_gemm_qkv(
    const u16* __restrict__ A, const u16* __restrict__ Bt,
    u16* __restrict__ Q, u16* __restrict__ Kb, u16* __restrict__ VT) {
  const int tm = blockIdx.x >> 5;
  const int tn = blockIdx.x & 31;
  __shared__ u16 sA[2 * BM * BK], sB[2 * BN * BK];
  f32x4 acc[4][4];
  acc_zero(acc);
  gemm_core_db(A + (size_t)tm * 128 * 2048, 2048, Bt + (size_t)tn * 128 * 2048, 2048, 32,
               1 << 28, sA, sB, acc);
  const int lane = threadIdx.x & 63, wave = threadIdx.x >> 6;
  const int wm = (wave >> 1) * 64, wn = (wave & 1) * 64;
  const int col = lane & 15, rb = (lane >> 4) * 4;
#pragma unroll
  for (int m = 0; m < 4; ++m)
#pragma unroll
    for (int n = 0; n < 4; ++n)
#pragma unroll
      for (int j = 0; j < 4; ++j) {
        int gm = tm * 128 + wm + m * 16 + rb + j;
        int gn = tn * 128 + wn + n * 16 + col;
        u16 bvv = f2bf(acc[m][n][j]);
        int b = gm >> 10, s = gm & 1023;
        if (gn < 2048) {
          int hh = gn >> 7, d = gn & 127;
          Q[(size_t)(((b * 16 + hh) << 10) + s) * 128 + d] = bvv;
        } else if (gn < 3072) {
          int kv = (gn - 2048) >> 7, d = gn & 127;
          Kb[(size_t)(((b * 8 + kv) << 10) + s) * 128 + d] = bvv;
        } else {
          int kv = (gn - 3072) >> 7, d = gn & 127;
          VT[(size_t)(((b * 8 + kv) << 7) + d) * 1024 + s] = bvv;
        }
      }
}

// ------------------------------------------------------------- generic GEMM + epilogue
// mode: 0 = Cf += C ; 1 = Cb = bf16(silu(C)) ; 2 = Cf += (mask[row]==0 ? C : 0)
__global__ __launch_bounds__(256) void k_gemm_epi(
    const u16* __restrict__ A, int lda, const u16* __restrict__ Bt, int ldb,
    int ksteps, int ntn, float* __restrict__ Cf, u16* __restrict__ Cb, int ldc,
    int mode, const int* __restrict__ mask) {
  const int tm = blockIdx.x / ntn;
  const int tn = blockIdx.x % ntn;
  __shared__ u16 sA[2 * BM * BK], sB[2 * BN * BK];
  f32x4 acc[4][4];
  acc_zero(acc);
  gemm_core_db(A + (size_t)tm * 128 * lda, lda, Bt + (size_t)tn * 128 * ldb, ldb, ksteps,
               1 << 28, sA, sB, acc);
  const int lane = threadIdx.x & 63, wave = threadIdx.x >> 6;
  const int wm = (wave >> 1) * 64, wn = (wave & 1) * 64;
  const int col = lane & 15, rb = (lane >> 4) * 4;
#pragma unroll
  for (int m = 0; m < 4; ++m)
#pragma unroll
    for (int n = 0; n < 4; ++n)
#pragma unroll
      for (int j = 0; j < 4; ++j) {
        int gm = tm * 128 + wm + m * 16 + rb + j;
        int gn = tn * 128 + wn + n * 16 + col;
        float v = acc[m][n][j];
        size_t idx = (size_t)gm * ldc + gn;
        if (mode == 0) {
          Cf[idx] += v;
        } else if (mode == 1) {
          float s = v / (1.f + __expf(-v));
          Cb[idx] = f2bf(s);
        } else {
          if (mask[gm] == 0) Cf[idx] += v;
        }
      }
}

// ------------------------------------------------------------- audio fc (compacted rows)
__global__ __launch_bounds__(256) void k_gemm_afc(
    const u16* __restrict__ Ax, const u16* __restrict__ Bt,
    u16* __restrict__ Cb, const int* __restrict__ cnt) {
  const int Na = cnt[0];
  const int tm = blockIdx.x >> 6;
  const int tn = blockIdx.x & 63;
  if (tm * 128 >= Na) return;
  __shared__ u16 sA[2 * BM * BK], sB[2 * BN * BK];
  f32x4 acc[4][4];
  acc_zero(acc);
  gemm_core_db(Ax + (size_t)tm * 128 * 2048, 2048, Bt + (size_t)tn * 128 * 2048, 2048, 32,
               Na - 1 - tm * 128, sA, sB, acc);
  const int lane = threadIdx.x & 63, wave = threadIdx.x >> 6;
  const int wm = (wave >> 1) * 64, wn = (wave & 1) * 64;
  const int col = lane & 15, rb = (lane >> 4) * 4;
#pragma unroll
  for (int m = 0; m < 4; ++m)
#pragma unroll
    for (int n = 0; n < 4; ++n)
#pragma unroll
      for (int j = 0; j < 4; ++j) {
        int gm = tm * 128 + wm + m * 16 + rb + j;
        int gn = tn * 128 + wn + n * 16 + col;
        if (gm < Na) {
          float v = acc[m][n][j];
          float s = v / (1.f + __expf(-v));
          Cb[(size_t)gm * 8192 + gn] = f2bf(s);
        }
      }
}

// ------------------------------------------------------------- audio proj (scatter-add)
__global__ __launch_bounds__(256) void k_gemm_aproj(
    const u16* __restrict__ A, const u16* __restrict__ Bt,
    float* __restrict__ h, const int* __restrict__ cnt, const int* __restrict__ cidx) {
  const int Na = cnt[0];
  const int tm = blockIdx.x >> 4;
  const int tn = blockIdx.x & 15;
  if (tm * 128 >= Na) return;
  __shared__ u16 sA[2 * BM * BK], sB[2 * BN * BK];
  f32x4 acc[4][4];
  acc_zero(acc);
  gemm_core_db(A + (size_t)tm * 128 * 8192, 8192, Bt + (size_t)tn * 128 * 8192, 8192, 128,
               Na - 1 - tm * 128, sA, sB, acc);
  const int lane = threadIdx.x & 63, wave = threadIdx.x >> 6;
  const int wm = (wave >> 1) * 64, wn = (wave & 1) * 64;
  const int col = lane & 15, rb = (lane >> 4) * 4;
#pragma unroll
  for (int m = 0; m < 4; ++m)
#pragma unroll
    for (int n = 0; n < 4; ++n)
#pragma unroll
      for (int j = 0; j < 4; ++j) {
        int gm = tm * 128 + wm + m * 16 + rb + j;
        int gn = tn * 128 + wn + n * 16 + col;
        if (gm < Na) h[(size_t)cidx[gm] * 2048 + gn] += acc[m][n][j];
      }
}

// ------------------------------------------------------------- scores (causal tiles)
__global__ __launch_bounds__(256) void k_scores(
    const u16* __restrict__ Q, const u16* __restrict__ Kb, float* __restrict__ S, int bh0) {
  const int zz = blockIdx.y;
  const int bh = bh0 + zz;
  const int b = bh >> 4, hq = bh & 15, kv = hq >> 1;
  int i = blockIdx.x;
  int tm = 0;
  while ((tm + 1) * (tm + 2) / 2 <= i) ++tm;
  int tn = i - tm * (tm + 1) / 2;
  __shared__ u16 sA[2 * BM * BK], sB[2 * BN * BK];
  f32x4 acc[4][4];
  acc_zero(acc);
  const u16* Aq = Q + ((size_t)(b * 16 + hq) * 1024 + tm * 128) * 128;
  const u16* Bk = Kb + ((size_t)(b * 8 + kv) * 1024 + tn * 128) * 128;
  gemm_core_db(Aq, 128, Bk, 128, 2, 1 << 28, sA, sB, acc);
  float* Sb = S + ((size_t)zz << 20);
  const int lane = threadIdx.x & 63, wave = threadIdx.x >> 6;
  const int wm = (wave >> 1) * 64, wn = (wave & 1) * 64;
  const int col = lane & 15, rb = (lane >> 4) * 4;
#pragma unroll
  for (int m = 0; m < 4; ++m)
#pragma unroll
    for (int n = 0; n < 4; ++n)
#pragma unroll
      for (int j = 0; j < 4; ++j)
        Sb[(size_t)(tm * 128 + wm + m * 16 + rb + j) * 1024 + tn * 128 + wn + n * 16 + col] =
            acc[m][n][j];
}

// ------------------------------------------------------------- row softmax -> bf16 P
__global__ __launch_bounds__(256) void k_softmax(const float* __restrict__ S, u16* __restrict__ P) {
  const int q = blockIdx.x;
  const int zz = blockIdx.y;
  const int tid = threadIdx.x;
  const float* row = S + ((size_t)zz << 20) + ((size_t)q << 10);
  u16* prow = P + ((size_t)zz << 20) + ((size_t)q << 10);
  const float scale = 0.08838834764831845f;
  float4 v = ((const float4*)row)[tid];
  const float* vf = (const float*)&v;
  float vals[4];
  float mx = -3.0e38f;
#pragma unroll
  for (int j = 0; j < 4; ++j) {
    int colj = tid * 4 + j;
    float t = (colj <= q) ? vf[j] * scale : -3.0e38f;
    vals[j] = t;
    mx = fmaxf(mx, t);
  }
  __shared__ float red[8];
#pragma unroll
  for (int o = 32; o; o >>= 1) mx = fmaxf(mx, __shfl_xor(mx, o));
  if ((tid & 63) == 0) red[tid >> 6] = mx;
  __syncthreads();
  mx = fmaxf(fmaxf(red[0], red[1]), fmaxf(red[2], red[3]));
  float e[4];
  float sum = 0.f;
#pragma unroll
  for (int j = 0; j < 4; ++j) {
    int colj = tid * 4 + j;
    e[j] = (colj <= q) ? __expf(vals[j] - mx) : 0.f;
    sum += e[j];
  }
#pragma unroll
  for (int o = 32; o; o >>= 1) sum += __shfl_xor(sum, o);
  if ((tid & 63) == 0) red[4 + (tid >> 6)] = sum;
  __syncthreads();
  float inv = 1.f / (red[4] + red[5] + red[6] + red[7]);
  u16x4 ov;
#pragma unroll
  for (int j = 0; j < 4; ++j) ov[j] = f2bf(e[j] * inv);
  *(u16x4*)&prow[tid * 4] = ov;
}

// ------------------------------------------------------------- PV (causal K limit)
__global__ __launch_bounds__(256) void k_pv(
    const u16* __restrict__ P, const u16* __restrict__ VT, u16* __restrict__ O, int bh0) {
  const int zz = blockIdx.y;
  const int bh = bh0 + zz;
  const int b = bh >> 4, hq = bh & 15, kv = hq >> 1;
  const int tm = blockIdx.x;
  __shared__ u16 sA[2 * BM * BK], sB[2 * BN * BK];
  f32x4 acc[4][4];
  acc_zero(acc);
  const u16* Ap = P + ((size_t)zz << 20) + (size_t)tm * 128 * 1024;
  const u16* Bv = VT + (size_t)(b * 8 + kv) * 128 * 1024;
  gemm_core_db(Ap, 1024, Bv, 1024, (tm + 1) * 2, 1 << 28, sA, sB, acc);
  const int lane = threadIdx.x & 63, wave = threadIdx.x >> 6;
  const int wm = (wave >> 1) * 64, wn = (wave & 1) * 64;
  const int col = lane & 15, rb = (lane >> 4) * 4;
#pragma unroll
  for (int m = 0; m < 4; ++m)
#pragma unroll
    for (int n = 0; n < 4; ++n)
#pragma unroll
      for (int j = 0; j < 4; ++j) {
        int s = tm * 128 + wm + m * 16 + rb + j;
        int d = wn + n * 16 + col;
        O[(size_t)(b * 1024 + s) * 2048 + hq * 128 + d] = f2bf(acc[m][n][j]);
      }
}

// ------------------------------------------------------------- transpose+convert W[K,N]f32 -> Wt[N,K]bf16
__global__ __launch_bounds__(256) void k_transpose(
    const float* __restrict__ W, u16* __restrict__ Wt, int K, int N) {
  __shared__ float tile[64][65];
  const int nk = K >> 6;
  const int tk = blockIdx.x % nk;
  const int tn = blockIdx.x / nk;
  const int tid = threadIdx.x;
#pragma unroll
  for (int i = 0; i < 16; ++i) {
    int u = i * 256 + tid;
    int r = u >> 6, c = u & 63;
    tile[r][c] = W[(size_t)(tk * 64 + r) * N + tn * 64 + c];
  }
  __syncthreads();
#pragma unroll
  for (int i = 0; i < 16; ++i) {
    int u = i * 256 + tid;
    int r = u >> 6, c = u & 63;
    Wt[(size_t)(tn * 64 + r) * K + tk * 64 + c] = f2bf(tile[c][r]);
  }
}

// ------------------------------------------------------------- mask scan (1 block)
__global__ __launch_bounds__(256) void k_scan(
    const int* __restrict__ mask, int* __restrict__ cpos,
    int* __restrict__ cidx, int* __restrict__ cnt) {
  const int tid = threadIdx.x;
  const int lane = tid & 63, wid = tid >> 6;
  int m[8];
  int s = 0;
#pragma unroll
  for (int j = 0; j < 8; ++j) { m[j] = mask[tid * 8 + j]; s += m[j]; }
  int ps = s;
#pragma unroll
  for (int o = 1; o < 64; o <<= 1) {
    int t = __shfl_up(ps, o);
    if (lane >= o) ps += t;
  }
  __shared__ int wsum[4];
  if (lane == 63) wsum[wid] = ps;
  __syncthreads();
  int base = 0;
  for (int w = 0; w < wid; ++w) base += wsum[w];
  int run = base + ps - s;
#pragma unroll
  for (int j = 0; j < 8; ++j) {
    int row = tid * 8 + j;
    cpos[row] = run;
    if (m[j]) cidx[run] = row;
    run += m[j];
  }
  if (tid == 255) cnt[0] = run;
}

// ------------------------------------------------------------- RMS norms
__device__ __forceinline__ float block_sum256(float v, float* red) {
  const int tid = threadIdx.x;
#pragma unroll
  for (int o = 32; o; o >>= 1) v += __shfl_xor(v, o);
  if ((tid & 63) == 0) red[tid >> 6] = v;
  __syncthreads();
  float r = red[0] + red[1] + red[2] + red[3];
  __syncthreads();
  return r;
}

// xc != null: out1 = rms*wt (dense); audio rows also write rms*wa to xc[cpos[row]]
// xc == null: out1 = rms * (mask ? wa : wt)
__global__ __launch_bounds__(256) void k_rms(
    const float* __restrict__ h, const float* __restrict__ wt, const float* __restrict__ wa,
    const int* __restrict__ mask, u16* __restrict__ out1, u16* __restrict__ xc,
    const int* __restrict__ cpos) {
  const int row = blockIdx.x;
  const int tid = threadIdx.x;
  const float* hr = h + (size_t)row * 2048;
  float4 v0 = ((const float4*)hr)[tid * 2];
  float4 v1 = ((const float4*)hr)[tid * 2 + 1];
  const float* f0 = (const float*)&v0;
  const float* f1 = (const float*)&v1;
  float ss = 0.f;
#pragma unroll
  for (int j = 0; j < 4; ++j) ss += f0[j] * f0[j] + f1[j] * f1[j];
  __shared__ float red[4];
  ss = block_sum256(ss, red);
  const float inv = rsqrtf(ss * (1.0f / 2048.0f) + 1e-5f);
  const int c0 = tid * 8;
  if (xc) {
    u16x8 a;
#pragma unroll
    for (int j = 0; j < 8; ++j) {
      float hv = (j < 4 ? f0[j] : f1[j - 4]) * inv;
      a[j] = f2bf(hv * wt[c0 + j]);
    }
    *(u16x8*)&out1[(size_t)row * 2048 + c0] = a;
    if (mask[row]) {
      u16x8 bb;
#pragma unroll
      for (int j = 0; j < 8; ++j) {
        float hv = (j < 4 ? f0[j] : f1[j - 4]) * inv;
        bb[j] = f2bf(hv * wa[c0 + j]);
      }
      *(u16x8*)&xc[(size_t)cpos[row] * 2048 + c0] = bb;
    }
  } else {
    const float* w = mask[row] ? wa : wt;
    u16x8 a;
#pragma unroll
    for (int j = 0; j < 8; ++j) {
      float hv = (j < 4 ? f0[j] : f1[j - 4]) * inv;
      a[j] = f2bf(hv * w[c0 + j]);
    }
    *(u16x8*)&out1[(size_t)row * 2048 + c0] = a;
  }
}

__global__ __launch_bounds__(256) void k_rms_final(
    const float* __restrict__ h, const float* __restrict__ w, float* __restrict__ out) {
  const int row = blockIdx.x;
  const int tid = threadIdx.x;
  const float* hr = h + (size_t)row * 2048;
  float4 v0 = ((const float4*)hr)[tid * 2];
  float4 v1 = ((const float4*)hr)[tid * 2 + 1];
  const float* f0 = (const float*)&v0;
  const float* f1 = (const float*)&v1;
  float ss = 0.f;
#pragma unroll
  for (int j = 0; j < 4; ++j) ss += f0[j] * f0[j] + f1[j] * f1[j];
  __shared__ float red[4];
  ss = block_sum256(ss, red);
  const float inv = rsqrtf(ss * (1.0f / 2048.0f) + 1e-5f);
  float4 o0, o1;
  float* p0 = (float*)&o0;
  float* p1 = (float*)&o1;
  const int c0 = tid * 8;
#pragma unroll
  for (int j = 0; j < 4; ++j) {
    p0[j] = f0[j] * inv * w[c0 + j];
    p1[j] = f1[j] * inv * w[c0 + 4 + j];
  }
  ((float4*)(out + (size_t)row * 2048))[tid * 2] = o0;
  ((float4*)(out + (size_t)row * 2048))[tid * 2 + 1] = o1;
}

// ------------------------------------------------------------- embedding
__global__ __launch_bounds__(256) void k_embed(
    const int* __restrict__ ids, const float* __restrict__ vocab,
    const float* __restrict__ audio, float* __restrict__ h, int* __restrict__ mask) {
  const int t = blockIdx.x;
  const int tid = threadIdx.x;
  const int id = ids[t];
  const int am = (id > 31999) ? 1 : 0;
  if (tid == 0) mask[t] = am;
  float* hr = h + (size_t)t * 2048;
  if (!am) {
    const float4* src = (const float4*)(vocab + (size_t)id * 2048);
    for (int j = tid; j < 512; j += 256) ((float4*)hr)[j] = src[j];
  } else {
    const int aid = id - 32000;
    for (int j = tid; j < 512; j += 256) {
      float4 s = {0.f, 0.f, 0.f, 0.f};
#pragma unroll
      for (int c = 0; c < 8; ++c) {
        float4 a = ((const float4*)(audio + (size_t)(aid + c * 1026) * 2048))[j];
        s.x += a.x; s.y += a.y; s.z += a.z; s.w += a.w;
      }
      ((float4*)hr)[j] = s;
    }
  }
}

// ------------------------------------------------------------- host launch
extern "C" void kernel_launch(void* const* d_in, const int* in_sizes, int n_in,
                              void* d_out, int out_size, void* d_ws, size_t ws_size,
                              hipStream_t stream) {
  const int* ids = (const int*)d_in[0];
  const float* vocab = (const float*)d_in[1];
  const float* audio = (const float*)d_in[2];
  const float* ln_in = (const float*)d_in[3];
  const float* ln_audio_in = (const float*)d_in[4];
  const float* ln_post = (const float*)d_in[5];
  const float* ln_audio_post = (const float*)d_in[6];
  const float* w_qkv = (const float*)d_in[7];
  const float* w_o = (const float*)d_in[8];
  const float* w_fc = (const float*)d_in[9];
  const float* w_proj = (const float*)d_in[10];
  const float* w_afc = (const float*)d_in[11];
  const float* w_aproj = (const float*)d_in[12];
  const float* ln_f = (const float*)d_in[13];
  float* out = (float*)d_out;

  char* p = (char*)d_ws;
  auto alloc = [&](size_t bytes) {
    char* r = p;
    p += (bytes + 255) & ~(size_t)255;
    return r;
  };
  float* h   = (float*)alloc((size_t)2048 * 2048 * 4);
  u16* x     = (u16*)alloc((size_t)2048 * 2048 * 2);
  u16* xc    = (u16*)alloc((size_t)2048 * 2048 * 2);
  u16* o     = (u16*)alloc((size_t)2048 * 2048 * 2);
  int* mask  = (int*)alloc((size_t)2048 * 4);
  int* cpos  = (int*)alloc((size_t)2048 * 4);
  int* cidx  = (int*)alloc((size_t)2048 * 4);
  int* cnt   = (int*)alloc((size_t)64 * 4);
  u16* Wt    = (u16*)alloc((size_t)8192 * 2048 * 2);
  u16* Q     = (u16*)alloc((size_t)2 * 16 * 1024 * 128 * 2);
  u16* Kb    = (u16*)alloc((size_t)2 * 8 * 1024 * 128 * 2);
  u16* VT    = (u16*)alloc((size_t)2 * 8 * 1024 * 128 * 2);
  float* S   = (float*)alloc((size_t)8 * 1024 * 1024 * 4);
  u16* P     = (u16*)alloc((size_t)8 * 1024 * 1024 * 2);
  u16* t1    = (u16*)alloc((size_t)2048 * 8192 * 2);
  (void)ws_size; (void)in_sizes; (void)n_in; (void)out_size;

  k_embed<<<2048, 256, 0, stream>>>(ids, vocab, audio, h, mask);
  k_scan<<<1, 256, 0, stream>>>(mask, cpos, cidx, cnt);

  for (int l = 0; l < 2; ++l) {
    // input norm (row-masked select)
    k_rms<<<2048, 256, 0, stream>>>(h, ln_in + l * 2048, ln_audio_in + l * 2048, mask, x,
                                    nullptr, nullptr);
    // qkv
    k_transpose<<<(2048 / 64) * (4096 / 64), 256, 0, stream>>>(
        w_qkv + (size_t)l * 2048 * 4096, Wt, 2048, 4096);
    k_gemm_qkv<<<16 * 32, 256, 0, stream>>>(x, Wt, Q, Kb, VT);
    // attention, 4 chunks of 8 (b,h)
    for (int c = 0; c < 4; ++c) {
      k_scores<<<dim3(36, 8), 256, 0, stream>>>(Q, Kb, S, c * 8);
      k_softmax<<<dim3(1024, 8), 256, 0, stream>>>(S, P);
      k_pv<<<dim3(8, 8), 256, 0, stream>>>(P, VT, o, c * 8);
    }
    // o-proj (+residual)
    k_transpose<<<(2048 / 64) * (2048 / 64), 256, 0, stream>>>(
        w_o + (size_t)l * 2048 * 2048, Wt, 2048, 2048);
    k_gemm_epi<<<16 * 16, 256, 0, stream>>>(o, 2048, Wt, 2048, 32, 16, h, nullptr, 2048, 0,
                                            nullptr);
    // post norm: dense text x, compacted audio xc
    k_rms<<<2048, 256, 0, stream>>>(h, ln_post + l * 2048, ln_audio_post + l * 2048, mask, x,
                                    xc, cpos);
    // text FFN (dense, masked add)
    k_transpose<<<(2048 / 64) * (8192 / 64), 256, 0, stream>>>(
        w_fc + (size_t)l * 2048 * 8192, Wt, 2048, 8192);
    k_gemm_epi<<<16 * 64, 256, 0, stream>>>(x, 2048, Wt, 2048, 32, 64, nullptr, t1, 8192, 1,
                                            nullptr);
    k_transpose<<<(8192 / 64) * (2048 / 64), 256, 0, stream>>>(
        w_proj + (size_t)l * 8192 * 2048, Wt, 8192, 2048);
    k_gemm_epi<<<16 * 16, 256, 0, stream>>>(t1, 8192, Wt, 8192, 128, 16, h, nullptr, 2048, 2,
                                            mask);
    // audio FFN (compacted rows, ~3% of tokens; blocks early-exit on count)
    k_transpose<<<(2048 / 64) * (8192 / 64), 256, 0, stream>>>(
        w_afc + (size_t)l * 2048 * 8192, Wt, 2048, 8192);
    k_gemm_afc<<<16 * 64, 256, 0, stream>>>(xc, Wt, t1, cnt);
    k_transpose<<<(8192 / 64) * (2048 / 64), 256, 0, stream>>>(
        w_aproj + (size_t)l * 8192 * 2048, Wt, 8192, 2048);
    k_gemm_aproj<<<16 * 16, 256, 0, stream>>>(t1, Wt, h, cnt, cidx);
  }

  k_rms_final<<<2048, 256, 0, stream>>>(h, ln_f, out);
}

// Round 3
// 1337.714 us; speedup vs baseline: 1.4896x; 1.4283x over previous
//
#include <hip/hip_runtime.h>
#include <hip/hip_bf16.h>

typedef unsigned short u16;
typedef __attribute__((ext_vector_type(4))) float f32x4;
typedef __attribute__((ext_vector_type(8))) short bf16x8;
typedef __attribute__((ext_vector_type(8))) unsigned short u16x8;
typedef __attribute__((ext_vector_type(4))) unsigned short u16x4;

#define BM 128
#define BN 128
#define BK 64

__device__ __forceinline__ u16 f2bf(float f) {
  union { float f; unsigned u; } v; v.f = f;
  unsigned r = v.u + 0x7FFFu + ((v.u >> 16) & 1u);
  return (u16)(r >> 16);
}

__device__ __forceinline__ void acc_zero(f32x4 acc[4][4]) {
#pragma unroll
  for (int m = 0; m < 4; ++m)
#pragma unroll
    for (int n = 0; n < 4; ++n)
      acc[m][n] = (f32x4){0.f, 0.f, 0.f, 0.f};
}

// ---------------------------------------------------------------- GEMM core
// Double-buffered 2-phase: STAGE(next) || compute(cur), one raw s_barrier +
// vmcnt(0) per K-step. LDS 2x(128x64) per operand = 64 KB (2 blocks/CU).
__device__ __forceinline__ void gemm_core_db(
    const u16* __restrict__ A, int lda,
    const u16* __restrict__ Bt, int ldb,
    int ksteps, int amax, u16* sA, u16* sB, f32x4 acc[4][4]) {
  const int tid = threadIdx.x;
  const int wave = tid >> 6;
  const int lane = tid & 63;
  const int r = tid >> 3;        // staging row base (+32 per i)
  const int ks = tid & 7;        // 16B segment within row
  const int wm = (wave >> 1) * 64;
  const int wn = (wave & 1) * 64;
  const int lr = lane & 15;
  const int lk = (lane >> 4) * 8;

  auto stage = [&](int buf, int kt) {
    const int k0 = kt * BK;
    u16* dA = sA + buf * 8192 + wave * 512;
    u16* dB = sB + buf * 8192 + wave * 512;
#pragma unroll
    for (int i = 0; i < 4; ++i) {
      int ra = i * 32 + r; if (ra > amax) ra = amax;
      __builtin_amdgcn_global_load_lds(
          (const __attribute__((address_space(1))) void*)(A + (size_t)ra * lda + k0 + ks * 8),
          (__attribute__((address_space(3))) void*)(dA + i * 2048), 16, 0, 0);
      __builtin_amdgcn_global_load_lds(
          (const __attribute__((address_space(1))) void*)(Bt + (size_t)(i * 32 + r) * ldb + k0 + ks * 8),
          (__attribute__((address_space(3))) void*)(dB + i * 2048), 16, 0, 0);
    }
  };

  stage(0, 0);
  asm volatile("s_waitcnt vmcnt(0)" ::: "memory");
  __builtin_amdgcn_s_barrier();
  __builtin_amdgcn_sched_barrier(0);

  for (int kt = 0; kt < ksteps; ++kt) {
    const int cur = kt & 1;
    if (kt + 1 < ksteps) stage(cur ^ 1, kt + 1);
    const u16* cA = sA + cur * 8192;
    const u16* cB = sB + cur * 8192;
#pragma unroll
    for (int kk = 0; kk < BK; kk += 32) {
      bf16x8 av[4], bv[4];
#pragma unroll
      for (int m = 0; m < 4; ++m)
        av[m] = *(const bf16x8*)&cA[(wm + m * 16 + lr) * BK + kk + lk];
#pragma unroll
      for (int n = 0; n < 4; ++n)
        bv[n] = *(const bf16x8*)&cB[(wn + n * 16 + lr) * BK + kk + lk];
#pragma unroll
      for (int m = 0; m < 4; ++m)
#pragma unroll
        for (int n = 0; n < 4; ++n)
          acc[m][n] = __builtin_amdgcn_mfma_f32_16x16x32_bf16(av[m], bv[n], acc[m][n], 0, 0, 0);
    }
    asm volatile("s_waitcnt vmcnt(0)" ::: "memory");
    __builtin_amdgcn_s_barrier();
    __builtin_amdgcn_sched_barrier(0);
  }
}

// ------------------------------------------------------------- QKV GEMM
__global__ __launch_bounds__(256) void k_gemm_qkv(
    const u16* __restrict__ A, const u16* __restrict__ Bt,
    u16* __restrict__ Q, u16* __restrict__ Kb, u16* __restrict__ VT) {
  const int tm = blockIdx.x >> 5;
  const int tn = blockIdx.x & 31;
  __shared__ u16 sA[2 * BM * BK], sB[2 * BN * BK];
  f32x4 acc[4][4];
  acc_zero(acc);
  gemm_core_db(A + (size_t)tm * 128 * 2048, 2048, Bt + (size_t)tn * 128 * 2048, 2048, 32,
               1 << 28, sA, sB, acc);
  const int lane = threadIdx.x & 63, wave = threadIdx.x >> 6;
  const int wm = (wave >> 1) * 64, wn = (wave & 1) * 64;
  const int col = lane & 15, rb = (lane >> 4) * 4;
#pragma unroll
  for (int m = 0; m < 4; ++m)
#pragma unroll
    for (int n = 0; n < 4; ++n)
#pragma unroll
      for (int j = 0; j < 4; ++j) {
        int gm = tm * 128 + wm + m * 16 + rb + j;
        int gn = tn * 128 + wn + n * 16 + col;
        u16 bvv = f2bf(acc[m][n][j]);
        int b = gm >> 10, s = gm & 1023;
        if (gn < 2048) {
          int hh = gn >> 7, d = gn & 127;
          Q[(size_t)(((b * 16 + hh) << 10) + s) * 128 + d] = bvv;
        } else if (gn < 3072) {
          int kv = (gn - 2048) >> 7, d = gn & 127;
          Kb[(size_t)(((b * 8 + kv) << 10) + s) * 128 + d] = bvv;
        } else {
          int kv = (gn - 3072) >> 7, d = gn & 127;
          VT[(size_t)(((b * 8 + kv) << 7) + d) * 1024 + s] = bvv;
        }
      }
}

// ------------------------------------------------------------- fc GEMM (silu -> bf16)
__global__ __launch_bounds__(256) void k_gemm_fc(
    const u16* __restrict__ A, const u16* __restrict__ Bt, u16* __restrict__ Cb) {
  const int tm = blockIdx.x >> 6;
  const int tn = blockIdx.x & 63;
  __shared__ u16 sA[2 * BM * BK], sB[2 * BN * BK];
  f32x4 acc[4][4];
  acc_zero(acc);
  gemm_core_db(A + (size_t)tm * 128 * 2048, 2048, Bt + (size_t)tn * 128 * 2048, 2048, 32,
               1 << 28, sA, sB, acc);
  const int lane = threadIdx.x & 63, wave = threadIdx.x >> 6;
  const int wm = (wave >> 1) * 64, wn = (wave & 1) * 64;
  const int col = lane & 15, rb = (lane >> 4) * 4;
#pragma unroll
  for (int m = 0; m < 4; ++m)
#pragma unroll
    for (int n = 0; n < 4; ++n)
#pragma unroll
      for (int j = 0; j < 4; ++j) {
        int gm = tm * 128 + wm + m * 16 + rb + j;
        int gn = tn * 128 + wn + n * 16 + col;
        float v = acc[m][n][j];
        float s = v / (1.f + __expf(-v));
        Cb[(size_t)gm * 8192 + gn] = f2bf(s);
      }
}

// ------------------------------------------------------------- generic split-K GEMM -> f32 partials
// grid: x = tn + ntn*ks, y = tm. Partial layout [nks][Mtot][ntn*128].
__global__ __launch_bounds__(256) void k_gemm_sk(
    const u16* __restrict__ A, int lda, const u16* __restrict__ Bt, int ldb,
    int ksteps, int ntn, float* __restrict__ Pp) {
  const int tn = blockIdx.x % ntn;
  const int ks = blockIdx.x / ntn;
  const int tm = blockIdx.y;
  const int Mtot = gridDim.y * 128;
  const int ldc = ntn * 128;
  const int k0 = ks * ksteps * BK;
  __shared__ u16 sA[2 * BM * BK], sB[2 * BN * BK];
  f32x4 acc[4][4];
  acc_zero(acc);
  gemm_core_db(A + (size_t)tm * 128 * lda + k0, lda, Bt + (size_t)tn * 128 * ldb + k0, ldb,
               ksteps, 1 << 28, sA, sB, acc);
  const int lane = threadIdx.x & 63, wave = threadIdx.x >> 6;
  const int wm = (wave >> 1) * 64, wn = (wave & 1) * 64;
  const int col = lane & 15, rb = (lane >> 4) * 4;
#pragma unroll
  for (int m = 0; m < 4; ++m)
#pragma unroll
    for (int n = 0; n < 4; ++n)
#pragma unroll
      for (int j = 0; j < 4; ++j) {
        int gm = tm * 128 + wm + m * 16 + rb + j;
        int gn = tn * 128 + wn + n * 16 + col;
        Pp[((size_t)ks * Mtot + gm) * ldc + gn] = acc[m][n][j];
      }
}

// ------------------------------------------------------------- compacted split-K GEMM (audio)
// grid: x = tn + ntn*ks, y = tm (<=2). Partial layout [nks][256][ntn*128].
__global__ __launch_bounds__(256) void k_gemm_cs(
    const u16* __restrict__ A, int lda, const u16* __restrict__ Bt, int ldb,
    int ksteps, int ntn, float* __restrict__ Pp, const int* __restrict__ cnt) {
  const int Na = cnt[0];
  const int tm = blockIdx.y;
  if (tm * 128 >= Na) return;
  const int tn = blockIdx.x % ntn;
  const int ks = blockIdx.x / ntn;
  const int ldc = ntn * 128;
  const int k0 = ks * ksteps * BK;
  __shared__ u16 sA[2 * BM * BK], sB[2 * BN * BK];
  f32x4 acc[4][4];
  acc_zero(acc);
  gemm_core_db(A + (size_t)tm * 128 * lda + k0, lda, Bt + (size_t)tn * 128 * ldb + k0, ldb,
               ksteps, Na - 1 - tm * 128, sA, sB, acc);
  const int lane = threadIdx.x & 63, wave = threadIdx.x >> 6;
  const int wm = (wave >> 1) * 64, wn = (wave & 1) * 64;
  const int col = lane & 15, rb = (lane >> 4) * 4;
#pragma unroll
  for (int m = 0; m < 4; ++m)
#pragma unroll
    for (int n = 0; n < 4; ++n)
#pragma unroll
      for (int j = 0; j < 4; ++j) {
        int gm = tm * 128 + wm + m * 16 + rb + j;
        int gn = tn * 128 + wn + n * 16 + col;
        Pp[((size_t)ks * 256 + gm) * ldc + gn] = acc[m][n][j];
      }
}

// ------------------------------------------------------------- reduces
// h[row] += P0+P1 (mode 0) / gated on mask[row]==0 (mode 2)
__global__ __launch_bounds__(256) void k_red2_add(
    float* __restrict__ h, const float* __restrict__ Pp,
    const int* __restrict__ mask, int mode) {
  const int row = blockIdx.y;
  if (mode == 2 && mask[row] != 0) return;
  const int c = blockIdx.x * 1024 + threadIdx.x * 4;
  const size_t i = (size_t)row * 2048 + c;
  float4 a = *(const float4*)&Pp[i];
  float4 b = *(const float4*)&Pp[(size_t)2048 * 2048 + i];
  float4 hv = *(float4*)&h[i];
  hv.x += a.x + b.x; hv.y += a.y + b.y; hv.z += a.z + b.z; hv.w += a.w + b.w;
  *(float4*)&h[i] = hv;
}

// t1[row] = bf16(silu(sum_4 Pafc)) for row < Na
__global__ __launch_bounds__(256) void k_red4_silu(
    const float* __restrict__ Pp, u16* __restrict__ t1, const int* __restrict__ cnt) {
  const int row = blockIdx.y;
  if (row >= cnt[0]) return;
  const int c = blockIdx.x * 1024 + threadIdx.x * 4;
  const size_t i = (size_t)row * 8192 + c;
  float4 s = *(const float4*)&Pp[i];
#pragma unroll
  for (int k = 1; k < 4; ++k) {
    float4 a = *(const float4*)&Pp[(size_t)k * 256 * 8192 + i];
    s.x += a.x; s.y += a.y; s.z += a.z; s.w += a.w;
  }
  u16x4 ov;
  const float* sf = (const float*)&s;
#pragma unroll
  for (int j = 0; j < 4; ++j) {
    float v = sf[j];
    ov[j] = f2bf(v / (1.f + __expf(-v)));
  }
  *(u16x4*)&t1[i] = ov;
}

// h[cidx[row]] += sum_8 Paproj for row < Na
__global__ __launch_bounds__(256) void k_red8_scatter(
    const float* __restrict__ Pp, float* __restrict__ h,
    const int* __restrict__ cnt, const int* __restrict__ cidx) {
  const int row = blockIdx.y;
  if (row >= cnt[0]) return;
  const int c = blockIdx.x * 1024 + threadIdx.x * 4;
  const size_t i = (size_t)row * 2048 + c;
  float4 s = *(const float4*)&Pp[i];
#pragma unroll
  for (int k = 1; k < 8; ++k) {
    float4 a = *(const float4*)&Pp[(size_t)k * 256 * 2048 + i];
    s.x += a.x; s.y += a.y; s.z += a.z; s.w += a.w;
  }
  const size_t o = (size_t)cidx[row] * 2048 + c;
  float4 hv = *(float4*)&h[o];
  hv.x += s.x; hv.y += s.y; hv.z += s.z; hv.w += s.w;
  *(float4*)&h[o] = hv;
}

// ------------------------------------------------------------- scores (causal tiles)
__global__ __launch_bounds__(256) void k_scores(
    const u16* __restrict__ Q, const u16* __restrict__ Kb, float* __restrict__ S, int bh0) {
  const int zz = blockIdx.y;
  const int bh = bh0 + zz;
  const int b = bh >> 4, hq = bh & 15, kv = hq >> 1;
  int i = blockIdx.x;
  int tm = 0;
  while ((tm + 1) * (tm + 2) / 2 <= i) ++tm;
  int tn = i - tm * (tm + 1) / 2;
  __shared__ u16 sA[2 * BM * BK], sB[2 * BN * BK];
  f32x4 acc[4][4];
  acc_zero(acc);
  const u16* Aq = Q + ((size_t)(b * 16 + hq) * 1024 + tm * 128) * 128;
  const u16* Bk = Kb + ((size_t)(b * 8 + kv) * 1024 + tn * 128) * 128;
  gemm_core_db(Aq, 128, Bk, 128, 2, 1 << 28, sA, sB, acc);
  float* Sb = S + ((size_t)zz << 20);
  const int lane = threadIdx.x & 63, wave = threadIdx.x >> 6;
  const int wm = (wave >> 1) * 64, wn = (wave & 1) * 64;
  const int col = lane & 15, rb = (lane >> 4) * 4;
#pragma unroll
  for (int m = 0; m < 4; ++m)
#pragma unroll
    for (int n = 0; n < 4; ++n)
#pragma unroll
      for (int j = 0; j < 4; ++j)
        Sb[(size_t)(tm * 128 + wm + m * 16 + rb + j) * 1024 + tn * 128 + wn + n * 16 + col] =
            acc[m][n][j];
}

// ------------------------------------------------------------- row softmax -> bf16 P
__global__ __launch_bounds__(256) void k_softmax(const float* __restrict__ S, u16* __restrict__ P) {
  const int q = blockIdx.x;
  const int zz = blockIdx.y;
  const int tid = threadIdx.x;
  const float* row = S + ((size_t)zz << 20) + ((size_t)q << 10);
  u16* prow = P + ((size_t)zz << 20) + ((size_t)q << 10);
  const float scale = 0.08838834764831845f;
  float4 v = ((const float4*)row)[tid];
  const float* vf = (const float*)&v;
  float vals[4];
  float mx = -3.0e38f;
#pragma unroll
  for (int j = 0; j < 4; ++j) {
    int colj = tid * 4 + j;
    float t = (colj <= q) ? vf[j] * scale : -3.0e38f;
    vals[j] = t;
    mx = fmaxf(mx, t);
  }
  __shared__ float red[8];
#pragma unroll
  for (int o = 32; o; o >>= 1) mx = fmaxf(mx, __shfl_xor(mx, o));
  if ((tid & 63) == 0) red[tid >> 6] = mx;
  __syncthreads();
  mx = fmaxf(fmaxf(red[0], red[1]), fmaxf(red[2], red[3]));
  float e[4];
  float sum = 0.f;
#pragma unroll
  for (int j = 0; j < 4; ++j) {
    int colj = tid * 4 + j;
    e[j] = (colj <= q) ? __expf(vals[j] - mx) : 0.f;
    sum += e[j];
  }
#pragma unroll
  for (int o = 32; o; o >>= 1) sum += __shfl_xor(sum, o);
  if ((tid & 63) == 0) red[4 + (tid >> 6)] = sum;
  __syncthreads();
  float inv = 1.f / (red[4] + red[5] + red[6] + red[7]);
  u16x4 ov;
#pragma unroll
  for (int j = 0; j < 4; ++j) ov[j] = f2bf(e[j] * inv);
  *(u16x4*)&prow[tid * 4] = ov;
}

// ------------------------------------------------------------- PV (causal K limit)
__global__ __launch_bounds__(256) void k_pv(
    const u16* __restrict__ P, const u16* __restrict__ VT, u16* __restrict__ O, int bh0) {
  const int zz = blockIdx.y;
  const int bh = bh0 + zz;
  const int b = bh >> 4, hq = bh & 15, kv = hq >> 1;
  const int tm = blockIdx.x;
  __shared__ u16 sA[2 * BM * BK], sB[2 * BN * BK];
  f32x4 acc[4][4];
  acc_zero(acc);
  const u16* Ap = P + ((size_t)zz << 20) + (size_t)tm * 128 * 1024;
  const u16* Bv = VT + (size_t)(b * 8 + kv) * 128 * 1024;
  gemm_core_db(Ap, 1024, Bv, 1024, (tm + 1) * 2, 1 << 28, sA, sB, acc);
  const int lane = threadIdx.x & 63, wave = threadIdx.x >> 6;
  const int wm = (wave >> 1) * 64, wn = (wave & 1) * 64;
  const int col = lane & 15, rb = (lane >> 4) * 4;
#pragma unroll
  for (int m = 0; m < 4; ++m)
#pragma unroll
    for (int n = 0; n < 4; ++n)
#pragma unroll
      for (int j = 0; j < 4; ++j) {
        int s = tm * 128 + wm + m * 16 + rb + j;
        int d = wn + n * 16 + col;
        O[(size_t)(b * 1024 + s) * 2048 + hq * 128 + d] = f2bf(acc[m][n][j]);
      }
}

// ------------------------------------------------------------- transpose+convert W[K,N]f32 -> Wt[N,K]bf16
__global__ __launch_bounds__(256) void k_transpose(
    const float* __restrict__ W, u16* __restrict__ Wt, int K, int N) {
  __shared__ float tile[64][65];
  const int nk = K >> 6;
  const int tk = blockIdx.x % nk;
  const int tn = blockIdx.x / nk;
  const int tid = threadIdx.x;
#pragma unroll
  for (int i = 0; i < 16; ++i) {
    int u = i * 256 + tid;
    int r = u >> 6, c = u & 63;
    tile[r][c] = W[(size_t)(tk * 64 + r) * N + tn * 64 + c];
  }
  __syncthreads();
#pragma unroll
  for (int i = 0; i < 16; ++i) {
    int u = i * 256 + tid;
    int r = u >> 6, c = u & 63;
    Wt[(size_t)(tn * 64 + r) * K + tk * 64 + c] = f2bf(tile[c][r]);
  }
}

// ------------------------------------------------------------- mask scan (1 block)
__global__ __launch_bounds__(256) void k_scan(
    const int* __restrict__ mask, int* __restrict__ cpos,
    int* __restrict__ cidx, int* __restrict__ cnt) {
  const int tid = threadIdx.x;
  const int lane = tid & 63, wid = tid >> 6;
  int m[8];
  int s = 0;
#pragma unroll
  for (int j = 0; j < 8; ++j) { m[j] = mask[tid * 8 + j]; s += m[j]; }
  int ps = s;
#pragma unroll
  for (int o = 1; o < 64; o <<= 1) {
    int t = __shfl_up(ps, o);
    if (lane >= o) ps += t;
  }
  __shared__ int wsum[4];
  if (lane == 63) wsum[wid] = ps;
  __syncthreads();
  int base = 0;
  for (int w = 0; w < wid; ++w) base += wsum[w];
  int run = base + ps - s;
#pragma unroll
  for (int j = 0; j < 8; ++j) {
    int row = tid * 8 + j;
    cpos[row] = run;
    if (m[j]) cidx[run] = row;
    run += m[j];
  }
  if (tid == 255) cnt[0] = run;
}

// ------------------------------------------------------------- RMS norms
__device__ __forceinline__ float block_sum256(float v, float* red) {
  const int tid = threadIdx.x;
#pragma unroll
  for (int o = 32; o; o >>= 1) v += __shfl_xor(v, o);
  if ((tid & 63) == 0) red[tid >> 6] = v;
  __syncthreads();
  float r = red[0] + red[1] + red[2] + red[3];
  __syncthreads();
  return r;
}

__global__ __launch_bounds__(256) void k_rms(
    const float* __restrict__ h, const float* __restrict__ wt, const float* __restrict__ wa,
    const int* __restrict__ mask, u16* __restrict__ out1, u16* __restrict__ xc,
    const int* __restrict__ cpos) {
  const int row = blockIdx.x;
  const int tid = threadIdx.x;
  const float* hr = h + (size_t)row * 2048;
  float4 v0 = ((const float4*)hr)[tid * 2];
  float4 v1 = ((const float4*)hr)[tid * 2 + 1];
  const float* f0 = (const float*)&v0;
  const float* f1 = (const float*)&v1;
  float ss = 0.f;
#pragma unroll
  for (int j = 0; j < 4; ++j) ss += f0[j] * f0[j] + f1[j] * f1[j];
  __shared__ float red[4];
  ss = block_sum256(ss, red);
  const float inv = rsqrtf(ss * (1.0f / 2048.0f) + 1e-5f);
  const int c0 = tid * 8;
  if (xc) {
    u16x8 a;
#pragma unroll
    for (int j = 0; j < 8; ++j) {
      float hv = (j < 4 ? f0[j] : f1[j - 4]) * inv;
      a[j] = f2bf(hv * wt[c0 + j]);
    }
    *(u16x8*)&out1[(size_t)row * 2048 + c0] = a;
    if (mask[row]) {
      u16x8 bb;
#pragma unroll
      for (int j = 0; j < 8; ++j) {
        float hv = (j < 4 ? f0[j] : f1[j - 4]) * inv;
        bb[j] = f2bf(hv * wa[c0 + j]);
      }
      *(u16x8*)&xc[(size_t)cpos[row] * 2048 + c0] = bb;
    }
  } else {
    const float* w = mask[row] ? wa : wt;
    u16x8 a;
#pragma unroll
    for (int j = 0; j < 8; ++j) {
      float hv = (j < 4 ? f0[j] : f1[j - 4]) * inv;
      a[j] = f2bf(hv * w[c0 + j]);
    }
    *(u16x8*)&out1[(size_t)row * 2048 + c0] = a;
  }
}

__global__ __launch_bounds__(256) void k_rms_final(
    const float* __restrict__ h, const float* __restrict__ w, float* __restrict__ out) {
  const int row = blockIdx.x;
  const int tid = threadIdx.x;
  const float* hr = h + (size_t)row * 2048;
  float4 v0 = ((const float4*)hr)[tid * 2];
  float4 v1 = ((const float4*)hr)[tid * 2 + 1];
  const float* f0 = (const float*)&v0;
  const float* f1 = (const float*)&v1;
  float ss = 0.f;
#pragma unroll
  for (int j = 0; j < 4; ++j) ss += f0[j] * f0[j] + f1[j] * f1[j];
  __shared__ float red[4];
  ss = block_sum256(ss, red);
  const float inv = rsqrtf(ss * (1.0f / 2048.0f) + 1e-5f);
  float4 o0, o1;
  float* p0 = (float*)&o0;
  float* p1 = (float*)&o1;
  const int c0 = tid * 8;
#pragma unroll
  for (int j = 0; j < 4; ++j) {
    p0[j] = f0[j] * inv * w[c0 + j];
    p1[j] = f1[j] * inv * w[c0 + 4 + j];
  }
  ((float4*)(out + (size_t)row * 2048))[tid * 2] = o0;
  ((float4*)(out + (size_t)row * 2048))[tid * 2 + 1] = o1;
}

// ------------------------------------------------------------- embedding
__global__ __launch_bounds__(256) void k_embed(
    const int* __restrict__ ids, const float* __restrict__ vocab,
    const float* __restrict__ audio, float* __restrict__ h, int* __restrict__ mask) {
  const int t = blockIdx.x;
  const int tid = threadIdx.x;
  const int id = ids[t];
  const int am = (id > 31999) ? 1 : 0;
  if (tid == 0) mask[t] = am;
  float* hr = h + (size_t)t * 2048;
  if (!am) {
    const float4* src = (const float4*)(vocab + (size_t)id * 2048);
    for (int j = tid; j < 512; j += 256) ((float4*)hr)[j] = src[j];
  } else {
    const int aid = id - 32000;
    for (int j = tid; j < 512; j += 256) {
      float4 s = {0.f, 0.f, 0.f, 0.f};
#pragma unroll
      for (int c = 0; c < 8; ++c) {
        float4 a = ((const float4*)(audio + (size_t)(aid + c * 1026) * 2048))[j];
        s.x += a.x; s.y += a.y; s.z += a.z; s.w += a.w;
      }
      ((float4*)hr)[j] = s;
    }
  }
}

// ------------------------------------------------------------- host launch
extern "C" void kernel_launch(void* const* d_in, const int* in_sizes, int n_in,
                              void* d_out, int out_size, void* d_ws, size_t ws_size,
                              hipStream_t stream) {
  const int* ids = (const int*)d_in[0];
  const float* vocab = (const float*)d_in[1];
  const float* audio = (const float*)d_in[2];
  const float* ln_in = (const float*)d_in[3];
  const float* ln_audio_in = (const float*)d_in[4];
  const float* ln_post = (const float*)d_in[5];
  const float* ln_audio_post = (const float*)d_in[6];
  const float* w_qkv = (const float*)d_in[7];
  const float* w_o = (const float*)d_in[8];
  const float* w_fc = (const float*)d_in[9];
  const float* w_proj = (const float*)d_in[10];
  const float* w_afc = (const float*)d_in[11];
  const float* w_aproj = (const float*)d_in[12];
  const float* ln_f = (const float*)d_in[13];
  float* out = (float*)d_out;

  char* p = (char*)d_ws;
  auto alloc = [&](size_t bytes) {
    char* r = p;
    p += (bytes + 255) & ~(size_t)255;
    return r;
  };
  float* h   = (float*)alloc((size_t)2048 * 2048 * 4);
  u16* x     = (u16*)alloc((size_t)2048 * 2048 * 2);
  u16* xc    = (u16*)alloc((size_t)2048 * 2048 * 2);
  u16* o     = (u16*)alloc((size_t)2048 * 2048 * 2);
  int* mask  = (int*)alloc((size_t)2048 * 4);
  int* cpos  = (int*)alloc((size_t)2048 * 4);
  int* cidx  = (int*)alloc((size_t)2048 * 4);
  int* cnt   = (int*)alloc((size_t)64 * 4);
  u16* Wt    = (u16*)alloc((size_t)8192 * 2048 * 2);
  u16* Q     = (u16*)alloc((size_t)2 * 16 * 1024 * 128 * 2);
  u16* Kb    = (u16*)alloc((size_t)2 * 8 * 1024 * 128 * 2);
  u16* VT    = (u16*)alloc((size_t)2 * 8 * 1024 * 128 * 2);
  float* S   = (float*)alloc((size_t)8 * 1024 * 1024 * 4);   // 33.55 MB, multi-use
  u16* P     = (u16*)alloc((size_t)8 * 1024 * 1024 * 2);     // 16.78 MB, multi-use
  u16* t1    = (u16*)alloc((size_t)2048 * 8192 * 2);
  // Aliases (sequential-in-stream reuse; attention S/P dead by FFN time):
  float* Psk   = S;           // [2][2048][2048] f32 split-K partials (o-proj / proj)
  float* Pafc  = S;           // [4][256][8192] f32 audio-fc partials
  float* Paprj = (float*)P;   // [8][256][2048] f32 audio-proj partials
  (void)ws_size; (void)in_sizes; (void)n_in; (void)out_size;

  k_embed<<<2048, 256, 0, stream>>>(ids, vocab, audio, h, mask);
  k_scan<<<1, 256, 0, stream>>>(mask, cpos, cidx, cnt);

  for (int l = 0; l < 2; ++l) {
    // input norm (row-masked select)
    k_rms<<<2048, 256, 0, stream>>>(h, ln_in + l * 2048, ln_audio_in + l * 2048, mask, x,
                                    nullptr, nullptr);
    // qkv
    k_transpose<<<(2048 / 64) * (4096 / 64), 256, 0, stream>>>(
        w_qkv + (size_t)l * 2048 * 4096, Wt, 2048, 4096);
    k_gemm_qkv<<<16 * 32, 256, 0, stream>>>(x, Wt, Q, Kb, VT);
    // attention, 4 chunks of 8 (b,h)
    for (int c = 0; c < 4; ++c) {
      k_scores<<<dim3(36, 8), 256, 0, stream>>>(Q, Kb, S, c * 8);
      k_softmax<<<dim3(1024, 8), 256, 0, stream>>>(S, P);
      k_pv<<<dim3(8, 8), 256, 0, stream>>>(P, VT, o, c * 8);
    }
    // o-proj: split-K x2 -> partials -> h += reduce
    k_transpose<<<(2048 / 64) * (2048 / 64), 256, 0, stream>>>(
        w_o + (size_t)l * 2048 * 2048, Wt, 2048, 2048);
    k_gemm_sk<<<dim3(16 * 2, 16), 256, 0, stream>>>(o, 2048, Wt, 2048, 16, 16, Psk);
    k_red2_add<<<dim3(2, 2048), 256, 0, stream>>>(h, Psk, nullptr, 0);
    // post norm: dense text x, compacted audio xc
    k_rms<<<2048, 256, 0, stream>>>(h, ln_post + l * 2048, ln_audio_post + l * 2048, mask, x,
                                    xc, cpos);
    // text FFN
    k_transpose<<<(2048 / 64) * (8192 / 64), 256, 0, stream>>>(
        w_fc + (size_t)l * 2048 * 8192, Wt, 2048, 8192);
    k_gemm_fc<<<16 * 64, 256, 0, stream>>>(x, Wt, t1);
    k_transpose<<<(8192 / 64) * (2048 / 64), 256, 0, stream>>>(
        w_proj + (size_t)l * 8192 * 2048, Wt, 8192, 2048);
    k_gemm_sk<<<dim3(16 * 2, 16), 256, 0, stream>>>(t1, 8192, Wt, 8192, 64, 16, Psk);
    k_red2_add<<<dim3(2, 2048), 256, 0, stream>>>(h, Psk, mask, 2);
    // audio FFN (compacted rows ~3%; split-K for parallelism)
    k_transpose<<<(2048 / 64) * (8192 / 64), 256, 0, stream>>>(
        w_afc + (size_t)l * 2048 * 8192, Wt, 2048, 8192);
    k_gemm_cs<<<dim3(64 * 4, 2), 256, 0, stream>>>(xc, 2048, Wt, 2048, 8, 64, Pafc, cnt);
    k_red4_silu<<<dim3(8, 256), 256, 0, stream>>>(Pafc, t1, cnt);
    k_transpose<<<(8192 / 64) * (2048 / 64), 256, 0, stream>>>(
        w_aproj + (size_t)l * 8192 * 2048, Wt, 8192, 2048);
    k_gemm_cs<<<dim3(16 * 8, 2), 256, 0, stream>>>(t1, 8192, Wt, 8192, 16, 16, Paprj, cnt);
    k_red8_scatter<<<dim3(2, 256), 256, 0, stream>>>(Paprj, h, cnt, cidx);
  }

  k_rms_final<<<2048, 256, 0, stream>>>(h, ln_f, out);
}

// Round 4
// 1147.184 us; speedup vs baseline: 1.7371x; 1.1661x over previous
//
#include <hip/hip_runtime.h>
#include <hip/hip_bf16.h>

typedef unsigned short u16;
typedef __attribute__((ext_vector_type(4))) float f32x4;
typedef __attribute__((ext_vector_type(8))) short bf16x8;
typedef __attribute__((ext_vector_type(8))) unsigned short u16x8;
typedef __attribute__((ext_vector_type(4))) unsigned short u16x4;

#define BM 128
#define BN 128
#define BK 64

__device__ __forceinline__ u16 f2bf(float f) {
  union { float f; unsigned u; } v; v.f = f;
  unsigned r = v.u + 0x7FFFu + ((v.u >> 16) & 1u);
  return (u16)(r >> 16);
}

__device__ __forceinline__ int xswz(int wg, int n) {  // bijective XCD swizzle, n%8==0
  return (wg & 7) * (n >> 3) + (wg >> 3);
}

// =================================================================== 8-phase 256^2 GEMM core
// 512 threads = 8 waves (2M x 4N), per-wave output 128x64 (8x4 fragments of 16x16).
// LDS 128 KiB: A[2buf][2half][128][64] bf16 + B[2buf][2half][128][64] bf16.
// Per K-tile (BK=64): 4 phases, each {ds_read quadrant (+B in ph0) | stage 1 half-tile |
//   barrier | lgkmcnt(0) | setprio(1) 16 MFMA setprio(0) | barrier}.
// Stage schedule: ph0/ph1 -> (g+1).A0/A1 (other buf; its old A dead since prev group end);
//                 ph2/ph3 -> (g+2).B0/B1 (current buf; B consumed in ph0 of this group).
// vmcnt(4) once per group (end of ph3): guarantees tile g+1 fully landed, keeps the
// 2 B-halves of tile g+2 in flight across barriers (counted-vmcnt, never drain mid-loop).
__device__ __forceinline__ void g8_stage_half(
    const u16* __restrict__ G, int ldg, int tile, int half, u16* ldsbase) {
  const int tid = threadIdx.x;
#pragma unroll
  for (int load = 0; load < 2; ++load) {
    int unit = load * 512 + tid;
    int row = unit >> 3, seg = unit & 7;
    __builtin_amdgcn_global_load_lds(
        (const __attribute__((address_space(1))) void*)(G + (size_t)(half * 128 + row) * ldg + tile * 64 + seg * 8),
        (__attribute__((address_space(3))) void*)(ldsbase + half * 8192 + load * 4096 + (tid >> 6) * 512),
        16, 0, 0);
  }
}

__device__ __forceinline__ void g8_core(
    const u16* __restrict__ A, int lda, const u16* __restrict__ Bt, int ldb,
    int NT, u16* lds, f32x4 acc[8][4]) {
  const int tid = threadIdx.x;
  const int lane = tid & 63;
  const int wid = tid >> 6;
  const int wr = wid >> 2, wc = wid & 3;
  const int lr = lane & 15, lk = (lane >> 4) * 8;

  u16* ldsA = lds;           // [buf][half][128][64]
  u16* ldsB = lds + 32768;

  // prologue: tile0 all 4 halves, tile1 B-halves
  g8_stage_half(A, lda, 0, 0, ldsA);
  g8_stage_half(A, lda, 0, 1, ldsA);
  g8_stage_half(Bt, ldb, 0, 0, ldsB);
  g8_stage_half(Bt, ldb, 0, 1, ldsB);
  if (NT > 1) {
    g8_stage_half(Bt, ldb, 1, 0, ldsB + 16384);
    g8_stage_half(Bt, ldb, 1, 1, ldsB + 16384);
  }
  asm volatile("s_waitcnt vmcnt(4)" ::: "memory");
  __builtin_amdgcn_s_barrier();
  __builtin_amdgcn_sched_barrier(0);

  for (int g = 0; g < NT; ++g) {
    const int buf = g & 1;
    const u16* cA = ldsA + buf * 16384 + wr * 8192;  // this wave's A half (128x64)
    const u16* cB = ldsB + buf * 16384;
    bf16x8 bv[4][2];
#pragma unroll
    for (int p = 0; p < 4; ++p) {
      bf16x8 av[2][2];
      if (p == 0) {
#pragma unroll
        for (int n = 0; n < 4; ++n)
#pragma unroll
          for (int kk = 0; kk < 2; ++kk) {
            int rg = wc * 64 + n * 16 + lr;
            bv[n][kk] = *(const bf16x8*)&cB[(rg >> 7) * 8192 + (rg & 127) * 64 + kk * 32 + lk];
          }
      }
#pragma unroll
      for (int m2 = 0; m2 < 2; ++m2)
#pragma unroll
        for (int kk = 0; kk < 2; ++kk)
          av[m2][kk] = *(const bf16x8*)&cA[((p * 2 + m2) * 16 + lr) * 64 + kk * 32 + lk];

      if (p == 0 && g + 1 < NT) g8_stage_half(A, lda, g + 1, 0, ldsA + ((g + 1) & 1) * 16384);
      if (p == 1 && g + 1 < NT) g8_stage_half(A, lda, g + 1, 1, ldsA + ((g + 1) & 1) * 16384);
      if (p == 2 && g + 2 < NT) g8_stage_half(Bt, ldb, g + 2, 0, ldsB + buf * 16384);
      if (p == 3) {
        if (g + 2 < NT) {
          g8_stage_half(Bt, ldb, g + 2, 1, ldsB + buf * 16384);
          asm volatile("s_waitcnt vmcnt(4)" ::: "memory");
        } else if (g + 1 < NT) {
          asm volatile("s_waitcnt vmcnt(0)" ::: "memory");
        }
      }
      __builtin_amdgcn_s_barrier();
      asm volatile("s_waitcnt lgkmcnt(0)" ::: "memory");
      __builtin_amdgcn_sched_barrier(0);
      __builtin_amdgcn_s_setprio(1);
#pragma unroll
      for (int m2 = 0; m2 < 2; ++m2)
#pragma unroll
        for (int n = 0; n < 4; ++n)
#pragma unroll
          for (int kk = 0; kk < 2; ++kk)
            acc[p * 2 + m2][n] = __builtin_amdgcn_mfma_f32_16x16x32_bf16(
                av[m2][kk], bv[n][kk], acc[p * 2 + m2][n], 0, 0, 0);
      __builtin_amdgcn_s_setprio(0);
      __builtin_amdgcn_sched_barrier(0);
      __builtin_amdgcn_s_barrier();
    }
  }
}

__device__ __forceinline__ void g8_acc_zero(f32x4 acc[8][4]) {
#pragma unroll
  for (int m = 0; m < 8; ++m)
#pragma unroll
    for (int n = 0; n < 4; ++n)
      acc[m][n] = (f32x4){0.f, 0.f, 0.f, 0.f};
}

// qkv split-K x2 -> f32 partials [2][2048][4096]
__global__ __launch_bounds__(512, 2) void k_gemm8_qkv(
    const u16* __restrict__ A, const u16* __restrict__ Bt, float* __restrict__ Pq) {
  __shared__ u16 lds[65536];
  const int wg = xswz(blockIdx.x, 256);
  const int ks = wg >> 7, rem = wg & 127;
  const int tm = rem >> 4, tn = rem & 15;
  f32x4 acc[8][4];
  g8_acc_zero(acc);
  g8_core(A + (size_t)tm * 256 * 2048 + ks * 1024, 2048,
          Bt + (size_t)tn * 256 * 2048 + ks * 1024, 2048, 16, lds, acc);
  const int lane = threadIdx.x & 63, wid = threadIdx.x >> 6;
  const int wr = wid >> 2, wc = wid & 3;
  const int col = lane & 15, rb = (lane >> 4) * 4;
#pragma unroll
  for (int m = 0; m < 8; ++m)
#pragma unroll
    for (int n = 0; n < 4; ++n)
#pragma unroll
      for (int j = 0; j < 4; ++j) {
        int gm = tm * 256 + wr * 128 + m * 16 + rb + j;
        int gn = tn * 256 + wc * 64 + n * 16 + col;
        Pq[((size_t)ks * 2048 + gm) * 4096 + gn] = acc[m][n][j];
      }
}

// fc: full K, silu -> bf16 t1[2048][8192]
__global__ __launch_bounds__(512, 2) void k_gemm8_fc(
    const u16* __restrict__ A, const u16* __restrict__ Bt, u16* __restrict__ Cb) {
  __shared__ u16 lds[65536];
  const int wg = xswz(blockIdx.x, 256);
  const int tm = wg >> 5, tn = wg & 31;
  f32x4 acc[8][4];
  g8_acc_zero(acc);
  g8_core(A + (size_t)tm * 256 * 2048, 2048, Bt + (size_t)tn * 256 * 2048, 2048, 32, lds, acc);
  const int lane = threadIdx.x & 63, wid = threadIdx.x >> 6;
  const int wr = wid >> 2, wc = wid & 3;
  const int col = lane & 15, rb = (lane >> 4) * 4;
#pragma unroll
  for (int m = 0; m < 8; ++m)
#pragma unroll
    for (int n = 0; n < 4; ++n)
#pragma unroll
      for (int j = 0; j < 4; ++j) {
        int gm = tm * 256 + wr * 128 + m * 16 + rb + j;
        int gn = tn * 256 + wc * 64 + n * 16 + col;
        float v = acc[m][n][j];
        Cb[(size_t)gm * 8192 + gn] = f2bf(v / (1.f + __expf(-v)));
      }
}

// generic split-K x4 (M=N=2048) -> f32 partials [4][2048][2048]
__global__ __launch_bounds__(512, 2) void k_gemm8_sk(
    const u16* __restrict__ A, int lda, const u16* __restrict__ Bt, int ldb,
    int NT, int koff, float* __restrict__ Pp) {
  __shared__ u16 lds[65536];
  const int wg = xswz(blockIdx.x, 256);
  const int ks = wg >> 6, rem = wg & 63;
  const int tm = rem >> 3, tn = rem & 7;
  f32x4 acc[8][4];
  g8_acc_zero(acc);
  g8_core(A + (size_t)tm * 256 * lda + ks * koff, lda,
          Bt + (size_t)tn * 256 * ldb + ks * koff, ldb, NT, lds, acc);
  const int lane = threadIdx.x & 63, wid = threadIdx.x >> 6;
  const int wr = wid >> 2, wc = wid & 3;
  const int col = lane & 15, rb = (lane >> 4) * 4;
#pragma unroll
  for (int m = 0; m < 8; ++m)
#pragma unroll
    for (int n = 0; n < 4; ++n)
#pragma unroll
      for (int j = 0; j < 4; ++j) {
        int gm = tm * 256 + wr * 128 + m * 16 + rb + j;
        int gn = tn * 256 + wc * 64 + n * 16 + col;
        Pp[((size_t)ks * 2048 + gm) * 2048 + gn] = acc[m][n][j];
      }
}

// qkv reduce: sum 2 partials, bf16, scatter into Q/K/VT
__global__ __launch_bounds__(256) void k_red_qkv(
    const float* __restrict__ Pq, u16* __restrict__ Q, u16* __restrict__ Kb,
    u16* __restrict__ VT) {
  const int gm = blockIdx.y;
  const int c = blockIdx.x * 1024 + threadIdx.x * 4;
  const size_t i = (size_t)gm * 4096 + c;
  float4 a = *(const float4*)&Pq[i];
  float4 b2 = *(const float4*)&Pq[(size_t)2048 * 4096 + i];
  const int b = gm >> 10, s = gm & 1023;
  u16 v[4];
  v[0] = f2bf(a.x + b2.x); v[1] = f2bf(a.y + b2.y);
  v[2] = f2bf(a.z + b2.z); v[3] = f2bf(a.w + b2.w);
  const int d = c & 127;
  if (c < 2048) {
    int hh = c >> 7;
    *(u16x4*)&Q[((size_t)((b * 16 + hh) * 1024 + s)) * 128 + d] = *(u16x4*)v;
  } else if (c < 3072) {
    int kv = (c - 2048) >> 7;
    *(u16x4*)&Kb[((size_t)((b * 8 + kv) * 1024 + s)) * 128 + d] = *(u16x4*)v;
  } else {
    int kv = (c - 3072) >> 7;
#pragma unroll
    for (int j = 0; j < 4; ++j)
      VT[((size_t)((b * 8 + kv) * 128 + d + j)) * 1024 + s] = v[j];
  }
}

// h += sum of 4 partials (mode 0) / gated on mask[row]==0 (mode 2)
__global__ __launch_bounds__(256) void k_red4_add(
    float* __restrict__ h, const float* __restrict__ Pp,
    const int* __restrict__ mask, int mode) {
  const int row = blockIdx.y;
  if (mode == 2 && mask[row] != 0) return;
  const int c = blockIdx.x * 1024 + threadIdx.x * 4;
  const size_t i = (size_t)row * 2048 + c;
  float4 s0 = *(const float4*)&Pp[i];
#pragma unroll
  for (int k = 1; k < 4; ++k) {
    float4 a = *(const float4*)&Pp[(size_t)k * 2048 * 2048 + i];
    s0.x += a.x; s0.y += a.y; s0.z += a.z; s0.w += a.w;
  }
  float4 hv = *(float4*)&h[i];
  hv.x += s0.x; hv.y += s0.y; hv.z += s0.z; hv.w += s0.w;
  *(float4*)&h[i] = hv;
}

// =================================================================== 128^2 2-phase core (attention + audio)
__device__ __forceinline__ void acc_zero(f32x4 acc[4][4]) {
#pragma unroll
  for (int m = 0; m < 4; ++m)
#pragma unroll
    for (int n = 0; n < 4; ++n)
      acc[m][n] = (f32x4){0.f, 0.f, 0.f, 0.f};
}

__device__ __forceinline__ void gemm_core_db(
    const u16* __restrict__ A, int lda,
    const u16* __restrict__ Bt, int ldb,
    int ksteps, int amax, u16* sA, u16* sB, f32x4 acc[4][4]) {
  const int tid = threadIdx.x;
  const int wave = tid >> 6;
  const int lane = tid & 63;
  const int r = tid >> 3;
  const int ks = tid & 7;
  const int wm = (wave >> 1) * 64;
  const int wn = (wave & 1) * 64;
  const int lr = lane & 15;
  const int lk = (lane >> 4) * 8;

  auto stage = [&](int buf, int kt) {
    const int k0 = kt * BK;
    u16* dA = sA + buf * 8192 + wave * 512;
    u16* dB = sB + buf * 8192 + wave * 512;
#pragma unroll
    for (int i = 0; i < 4; ++i) {
      int ra = i * 32 + r; if (ra > amax) ra = amax;
      __builtin_amdgcn_global_load_lds(
          (const __attribute__((address_space(1))) void*)(A + (size_t)ra * lda + k0 + ks * 8),
          (__attribute__((address_space(3))) void*)(dA + i * 2048), 16, 0, 0);
      __builtin_amdgcn_global_load_lds(
          (const __attribute__((address_space(1))) void*)(Bt + (size_t)(i * 32 + r) * ldb + k0 + ks * 8),
          (__attribute__((address_space(3))) void*)(dB + i * 2048), 16, 0, 0);
    }
  };

  stage(0, 0);
  asm volatile("s_waitcnt vmcnt(0)" ::: "memory");
  __builtin_amdgcn_s_barrier();
  __builtin_amdgcn_sched_barrier(0);

  for (int kt = 0; kt < ksteps; ++kt) {
    const int cur = kt & 1;
    if (kt + 1 < ksteps) stage(cur ^ 1, kt + 1);
    const u16* cA = sA + cur * 8192;
    const u16* cB = sB + cur * 8192;
#pragma unroll
    for (int kk = 0; kk < BK; kk += 32) {
      bf16x8 av[4], bv[4];
#pragma unroll
      for (int m = 0; m < 4; ++m)
        av[m] = *(const bf16x8*)&cA[(wm + m * 16 + lr) * BK + kk + lk];
#pragma unroll
      for (int n = 0; n < 4; ++n)
        bv[n] = *(const bf16x8*)&cB[(wn + n * 16 + lr) * BK + kk + lk];
#pragma unroll
      for (int m = 0; m < 4; ++m)
#pragma unroll
        for (int n = 0; n < 4; ++n)
          acc[m][n] = __builtin_amdgcn_mfma_f32_16x16x32_bf16(av[m], bv[n], acc[m][n], 0, 0, 0);
    }
    asm volatile("s_waitcnt vmcnt(0)" ::: "memory");
    __builtin_amdgcn_s_barrier();
    __builtin_amdgcn_sched_barrier(0);
  }
}

// ------------------------------------------------------------- audio fc/proj (compacted split-K)
__global__ __launch_bounds__(256) void k_gemm_cs(
    const u16* __restrict__ A, int lda, const u16* __restrict__ Bt, int ldb,
    int ksteps, int ntn, float* __restrict__ Pp, const int* __restrict__ cnt) {
  const int Na = cnt[0];
  const int tm = blockIdx.y;
  if (tm * 128 >= Na) return;
  const int tn = blockIdx.x % ntn;
  const int ks = blockIdx.x / ntn;
  const int ldc = ntn * 128;
  const int k0 = ks * ksteps * BK;
  __shared__ u16 sA[2 * BM * BK], sB[2 * BN * BK];
  f32x4 acc[4][4];
  acc_zero(acc);
  gemm_core_db(A + (size_t)tm * 128 * lda + k0, lda, Bt + (size_t)tn * 128 * ldb + k0, ldb,
               ksteps, Na - 1 - tm * 128, sA, sB, acc);
  const int lane = threadIdx.x & 63, wave = threadIdx.x >> 6;
  const int wm = (wave >> 1) * 64, wn = (wave & 1) * 64;
  const int col = lane & 15, rb = (lane >> 4) * 4;
#pragma unroll
  for (int m = 0; m < 4; ++m)
#pragma unroll
    for (int n = 0; n < 4; ++n)
#pragma unroll
      for (int j = 0; j < 4; ++j) {
        int gm = tm * 128 + wm + m * 16 + rb + j;
        int gn = tn * 128 + wn + n * 16 + col;
        Pp[((size_t)ks * 256 + gm) * ldc + gn] = acc[m][n][j];
      }
}

__global__ __launch_bounds__(256) void k_red4_silu(
    const float* __restrict__ Pp, u16* __restrict__ t1, const int* __restrict__ cnt) {
  const int row = blockIdx.y;
  if (row >= cnt[0]) return;
  const int c = blockIdx.x * 1024 + threadIdx.x * 4;
  const size_t i = (size_t)row * 8192 + c;
  float4 s = *(const float4*)&Pp[i];
#pragma unroll
  for (int k = 1; k < 4; ++k) {
    float4 a = *(const float4*)&Pp[(size_t)k * 256 * 8192 + i];
    s.x += a.x; s.y += a.y; s.z += a.z; s.w += a.w;
  }
  u16x4 ov;
  const float* sf = (const float*)&s;
#pragma unroll
  for (int j = 0; j < 4; ++j) {
    float v = sf[j];
    ov[j] = f2bf(v / (1.f + __expf(-v)));
  }
  *(u16x4*)&t1[i] = ov;
}

__global__ __launch_bounds__(256) void k_red8_scatter(
    const float* __restrict__ Pp, float* __restrict__ h,
    const int* __restrict__ cnt, const int* __restrict__ cidx) {
  const int row = blockIdx.y;
  if (row >= cnt[0]) return;
  const int c = blockIdx.x * 1024 + threadIdx.x * 4;
  const size_t i = (size_t)row * 2048 + c;
  float4 s = *(const float4*)&Pp[i];
#pragma unroll
  for (int k = 1; k < 8; ++k) {
    float4 a = *(const float4*)&Pp[(size_t)k * 256 * 2048 + i];
    s.x += a.x; s.y += a.y; s.z += a.z; s.w += a.w;
  }
  const size_t o = (size_t)cidx[row] * 2048 + c;
  float4 hv = *(float4*)&h[o];
  hv.x += s.x; hv.y += s.y; hv.z += s.z; hv.w += s.w;
  *(float4*)&h[o] = hv;
}

// ------------------------------------------------------------- attention
__global__ __launch_bounds__(256) void k_scores(
    const u16* __restrict__ Q, const u16* __restrict__ Kb, float* __restrict__ S) {
  const int bh = blockIdx.y;
  const int b = bh >> 4, hq = bh & 15, kv = hq >> 1;
  int i = blockIdx.x;
  int tm = 0;
  while ((tm + 1) * (tm + 2) / 2 <= i) ++tm;
  int tn = i - tm * (tm + 1) / 2;
  __shared__ u16 sA[2 * BM * BK], sB[2 * BN * BK];
  f32x4 acc[4][4];
  acc_zero(acc);
  const u16* Aq = Q + ((size_t)(b * 16 + hq) * 1024 + tm * 128) * 128;
  const u16* Bk = Kb + ((size_t)(b * 8 + kv) * 1024 + tn * 128) * 128;
  gemm_core_db(Aq, 128, Bk, 128, 2, 1 << 28, sA, sB, acc);
  float* Sb = S + ((size_t)bh << 20);
  const int lane = threadIdx.x & 63, wave = threadIdx.x >> 6;
  const int wm = (wave >> 1) * 64, wn = (wave & 1) * 64;
  const int col = lane & 15, rb = (lane >> 4) * 4;
#pragma unroll
  for (int m = 0; m < 4; ++m)
#pragma unroll
    for (int n = 0; n < 4; ++n)
#pragma unroll
      for (int j = 0; j < 4; ++j)
        Sb[(size_t)(tm * 128 + wm + m * 16 + rb + j) * 1024 + tn * 128 + wn + n * 16 + col] =
            acc[m][n][j];
}

__global__ __launch_bounds__(256) void k_softmax(const float* __restrict__ S, u16* __restrict__ P) {
  const int q = blockIdx.x;
  const int zz = blockIdx.y;
  const int tid = threadIdx.x;
  const float* row = S + ((size_t)zz << 20) + ((size_t)q << 10);
  u16* prow = P + ((size_t)zz << 20) + ((size_t)q << 10);
  const float scale = 0.08838834764831845f;
  float4 v = ((const float4*)row)[tid];
  const float* vf = (const float*)&v;
  float vals[4];
  float mx = -3.0e38f;
#pragma unroll
  for (int j = 0; j < 4; ++j) {
    int colj = tid * 4 + j;
    float t = (colj <= q) ? vf[j] * scale : -3.0e38f;
    vals[j] = t;
    mx = fmaxf(mx, t);
  }
  __shared__ float red[8];
#pragma unroll
  for (int o = 32; o; o >>= 1) mx = fmaxf(mx, __shfl_xor(mx, o));
  if ((tid & 63) == 0) red[tid >> 6] = mx;
  __syncthreads();
  mx = fmaxf(fmaxf(red[0], red[1]), fmaxf(red[2], red[3]));
  float e[4];
  float sum = 0.f;
#pragma unroll
  for (int j = 0; j < 4; ++j) {
    int colj = tid * 4 + j;
    e[j] = (colj <= q) ? __expf(vals[j] - mx) : 0.f;
    sum += e[j];
  }
#pragma unroll
  for (int o = 32; o; o >>= 1) sum += __shfl_xor(sum, o);
  if ((tid & 63) == 0) red[4 + (tid >> 6)] = sum;
  __syncthreads();
  float inv = 1.f / (red[4] + red[5] + red[6] + red[7]);
  u16x4 ov;
#pragma unroll
  for (int j = 0; j < 4; ++j) ov[j] = f2bf(e[j] * inv);
  *(u16x4*)&prow[tid * 4] = ov;
}

__global__ __launch_bounds__(256) void k_pv(
    const u16* __restrict__ P, const u16* __restrict__ VT, u16* __restrict__ O) {
  const int bh = blockIdx.y;
  const int b = bh >> 4, hq = bh & 15, kv = hq >> 1;
  const int tm = blockIdx.x;
  __shared__ u16 sA[2 * BM * BK], sB[2 * BN * BK];
  f32x4 acc[4][4];
  acc_zero(acc);
  const u16* Ap = P + ((size_t)bh << 20) + (size_t)tm * 128 * 1024;
  const u16* Bv = VT + (size_t)(b * 8 + kv) * 128 * 1024;
  gemm_core_db(Ap, 1024, Bv, 1024, (tm + 1) * 2, 1 << 28, sA, sB, acc);
  const int lane = threadIdx.x & 63, wave = threadIdx.x >> 6;
  const int wm = (wave >> 1) * 64, wn = (wave & 1) * 64;
  const int col = lane & 15, rb = (lane >> 4) * 4;
#pragma unroll
  for (int m = 0; m < 4; ++m)
#pragma unroll
    for (int n = 0; n < 4; ++n)
#pragma unroll
      for (int j = 0; j < 4; ++j) {
        int s = tm * 128 + wm + m * 16 + rb + j;
        int d = wn + n * 16 + col;
        O[(size_t)(b * 1024 + s) * 2048 + hq * 128 + d] = f2bf(acc[m][n][j]);
      }
}

// ------------------------------------------------------------- transpose W[K,N]f32 -> Wt[N,K]bf16
__global__ __launch_bounds__(256) void k_transpose(
    const float* __restrict__ W, u16* __restrict__ Wt, int K, int N) {
  __shared__ float tile[64][65];
  const int nk = K >> 6;
  const int tk = blockIdx.x % nk;
  const int tn = blockIdx.x / nk;
  const int tid = threadIdx.x;
#pragma unroll
  for (int i = 0; i < 16; ++i) {
    int u = i * 256 + tid;
    int r = u >> 6, c = u & 63;
    tile[r][c] = W[(size_t)(tk * 64 + r) * N + tn * 64 + c];
  }
  __syncthreads();
#pragma unroll
  for (int i = 0; i < 16; ++i) {
    int u = i * 256 + tid;
    int r = u >> 6, c = u & 63;
    Wt[(size_t)(tn * 64 + r) * K + tk * 64 + c] = f2bf(tile[c][r]);
  }
}

// ------------------------------------------------------------- mask scan (1 block)
__global__ __launch_bounds__(256) void k_scan(
    const int* __restrict__ mask, int* __restrict__ cpos,
    int* __restrict__ cidx, int* __restrict__ cnt) {
  const int tid = threadIdx.x;
  const int lane = tid & 63, wid = tid >> 6;
  int m[8];
  int s = 0;
#pragma unroll
  for (int j = 0; j < 8; ++j) { m[j] = mask[tid * 8 + j]; s += m[j]; }
  int ps = s;
#pragma unroll
  for (int o = 1; o < 64; o <<= 1) {
    int t = __shfl_up(ps, o);
    if (lane >= o) ps += t;
  }
  __shared__ int wsum[4];
  if (lane == 63) wsum[wid] = ps;
  __syncthreads();
  int base = 0;
  for (int w = 0; w < wid; ++w) base += wsum[w];
  int run = base + ps - s;
#pragma unroll
  for (int j = 0; j < 8; ++j) {
    int row = tid * 8 + j;
    cpos[row] = run;
    if (m[j]) cidx[run] = row;
    run += m[j];
  }
  if (tid == 255) cnt[0] = run;
}

// ------------------------------------------------------------- RMS norms
__device__ __forceinline__ float block_sum256(float v, float* red) {
  const int tid = threadIdx.x;
#pragma unroll
  for (int o = 32; o; o >>= 1) v += __shfl_xor(v, o);
  if ((tid & 63) == 0) red[tid >> 6] = v;
  __syncthreads();
  float r = red[0] + red[1] + red[2] + red[3];
  __syncthreads();
  return r;
}

__global__ __launch_bounds__(256) void k_rms(
    const float* __restrict__ h, const float* __restrict__ wt, const float* __restrict__ wa,
    const int* __restrict__ mask, u16* __restrict__ out1, u16* __restrict__ xc,
    const int* __restrict__ cpos) {
  const int row = blockIdx.x;
  const int tid = threadIdx.x;
  const float* hr = h + (size_t)row * 2048;
  float4 v0 = ((const float4*)hr)[tid * 2];
  float4 v1 = ((const float4*)hr)[tid * 2 + 1];
  const float* f0 = (const float*)&v0;
  const float* f1 = (const float*)&v1;
  float ss = 0.f;
#pragma unroll
  for (int j = 0; j < 4; ++j) ss += f0[j] * f0[j] + f1[j] * f1[j];
  __shared__ float red[4];
  ss = block_sum256(ss, red);
  const float inv = rsqrtf(ss * (1.0f / 2048.0f) + 1e-5f);
  const int c0 = tid * 8;
  if (xc) {
    u16x8 a;
#pragma unroll
    for (int j = 0; j < 8; ++j) {
      float hv = (j < 4 ? f0[j] : f1[j - 4]) * inv;
      a[j] = f2bf(hv * wt[c0 + j]);
    }
    *(u16x8*)&out1[(size_t)row * 2048 + c0] = a;
    if (mask[row]) {
      u16x8 bb;
#pragma unroll
      for (int j = 0; j < 8; ++j) {
        float hv = (j < 4 ? f0[j] : f1[j - 4]) * inv;
        bb[j] = f2bf(hv * wa[c0 + j]);
      }
      *(u16x8*)&xc[(size_t)cpos[row] * 2048 + c0] = bb;
    }
  } else {
    const float* w = mask[row] ? wa : wt;
    u16x8 a;
#pragma unroll
    for (int j = 0; j < 8; ++j) {
      float hv = (j < 4 ? f0[j] : f1[j - 4]) * inv;
      a[j] = f2bf(hv * w[c0 + j]);
    }
    *(u16x8*)&out1[(size_t)row * 2048 + c0] = a;
  }
}

__global__ __launch_bounds__(256) void k_rms_final(
    const float* __restrict__ h, const float* __restrict__ w, float* __restrict__ out) {
  const int row = blockIdx.x;
  const int tid = threadIdx.x;
  const float* hr = h + (size_t)row * 2048;
  float4 v0 = ((const float4*)hr)[tid * 2];
  float4 v1 = ((const float4*)hr)[tid * 2 + 1];
  const float* f0 = (const float*)&v0;
  const float* f1 = (const float*)&v1;
  float ss = 0.f;
#pragma unroll
  for (int j = 0; j < 4; ++j) ss += f0[j] * f0[j] + f1[j] * f1[j];
  __shared__ float red[4];
  ss = block_sum256(ss, red);
  const float inv = rsqrtf(ss * (1.0f / 2048.0f) + 1e-5f);
  float4 o0, o1;
  float* p0 = (float*)&o0;
  float* p1 = (float*)&o1;
  const int c0 = tid * 8;
#pragma unroll
  for (int j = 0; j < 4; ++j) {
    p0[j] = f0[j] * inv * w[c0 + j];
    p1[j] = f1[j] * inv * w[c0 + 4 + j];
  }
  ((float4*)(out + (size_t)row * 2048))[tid * 2] = o0;
  ((float4*)(out + (size_t)row * 2048))[tid * 2 + 1] = o1;
}

// ------------------------------------------------------------- embedding
__global__ __launch_bounds__(256) void k_embed(
    const int* __restrict__ ids, const float* __restrict__ vocab,
    const float* __restrict__ audio, float* __restrict__ h, int* __restrict__ mask) {
  const int t = blockIdx.x;
  const int tid = threadIdx.x;
  const int id = ids[t];
  const int am = (id > 31999) ? 1 : 0;
  if (tid == 0) mask[t] = am;
  float* hr = h + (size_t)t * 2048;
  if (!am) {
    const float4* src = (const float4*)(vocab + (size_t)id * 2048);
    for (int j = tid; j < 512; j += 256) ((float4*)hr)[j] = src[j];
  } else {
    const int aid = id - 32000;
    for (int j = tid; j < 512; j += 256) {
      float4 s = {0.f, 0.f, 0.f, 0.f};
#pragma unroll
      for (int c = 0; c < 8; ++c) {
        float4 a = ((const float4*)(audio + (size_t)(aid + c * 1026) * 2048))[j];
        s.x += a.x; s.y += a.y; s.z += a.z; s.w += a.w;
      }
      ((float4*)hr)[j] = s;
    }
  }
}

// ------------------------------------------------------------- host launch
extern "C" void kernel_launch(void* const* d_in, const int* in_sizes, int n_in,
                              void* d_out, int out_size, void* d_ws, size_t ws_size,
                              hipStream_t stream) {
  const int* ids = (const int*)d_in[0];
  const float* vocab = (const float*)d_in[1];
  const float* audio = (const float*)d_in[2];
  const float* ln_in = (const float*)d_in[3];
  const float* ln_audio_in = (const float*)d_in[4];
  const float* ln_post = (const float*)d_in[5];
  const float* ln_audio_post = (const float*)d_in[6];
  const float* w_qkv = (const float*)d_in[7];
  const float* w_o = (const float*)d_in[8];
  const float* w_fc = (const float*)d_in[9];
  const float* w_proj = (const float*)d_in[10];
  const float* w_afc = (const float*)d_in[11];
  const float* w_aproj = (const float*)d_in[12];
  const float* ln_f = (const float*)d_in[13];
  float* out = (float*)d_out;

  char* p = (char*)d_ws;
  auto alloc = [&](size_t bytes) {
    char* r = p;
    p += (bytes + 255) & ~(size_t)255;
    return r;
  };
  float* h   = (float*)alloc((size_t)2048 * 2048 * 4);
  u16* x     = (u16*)alloc((size_t)2048 * 2048 * 2);
  u16* xc    = (u16*)alloc((size_t)2048 * 2048 * 2);
  u16* o     = (u16*)alloc((size_t)2048 * 2048 * 2);
  int* mask  = (int*)alloc((size_t)2048 * 4);
  int* cpos  = (int*)alloc((size_t)2048 * 4);
  int* cidx  = (int*)alloc((size_t)2048 * 4);
  int* cnt   = (int*)alloc((size_t)64 * 4);
  u16* Wt    = (u16*)alloc((size_t)8192 * 2048 * 2);
  u16* Q     = (u16*)alloc((size_t)2 * 16 * 1024 * 128 * 2);
  u16* Kb    = (u16*)alloc((size_t)2 * 8 * 1024 * 128 * 2);
  u16* VT    = (u16*)alloc((size_t)2 * 8 * 1024 * 128 * 2);
  float* S   = (float*)alloc((size_t)32 * 1024 * 1024 * 4);  // 134 MB: scores + f32 partial alias
  u16* P     = (u16*)alloc((size_t)32 * 1024 * 1024 * 2);    // 67 MB: probs + audio-proj partials
  u16* t1    = (u16*)alloc((size_t)2048 * 8192 * 2);
  // Sequential-in-stream aliases:
  float* Pq    = S;          // [2][2048][4096] f32 qkv split-K partials (before scores)
  float* Psk   = S;          // [4][2048][2048] f32 o/proj split-K partials (after softmax)
  float* Pafc  = S;          // [4][256][8192] f32 audio-fc partials
  float* Paprj = (float*)P;  // [8][256][2048] f32 audio-proj partials (after pv)
  (void)ws_size; (void)in_sizes; (void)n_in; (void)out_size;

  k_embed<<<2048, 256, 0, stream>>>(ids, vocab, audio, h, mask);
  k_scan<<<1, 256, 0, stream>>>(mask, cpos, cidx, cnt);

  for (int l = 0; l < 2; ++l) {
    // input norm (row-masked select)
    k_rms<<<2048, 256, 0, stream>>>(h, ln_in + l * 2048, ln_audio_in + l * 2048, mask, x,
                                    nullptr, nullptr);
    // qkv: 8-phase split-K x2 -> partials -> scatter reduce
    k_transpose<<<(2048 / 64) * (4096 / 64), 256, 0, stream>>>(
        w_qkv + (size_t)l * 2048 * 4096, Wt, 2048, 4096);
    k_gemm8_qkv<<<256, 512, 0, stream>>>(x, Wt, Pq);
    k_red_qkv<<<dim3(4, 2048), 256, 0, stream>>>(Pq, Q, Kb, VT);
    // attention, single pass over all 32 (b,h)
    k_scores<<<dim3(36, 32), 256, 0, stream>>>(Q, Kb, S);
    k_softmax<<<dim3(1024, 32), 256, 0, stream>>>(S, P);
    k_pv<<<dim3(8, 32), 256, 0, stream>>>(P, VT, o);
    // o-proj: 8-phase split-K x4 -> h += reduce
    k_transpose<<<(2048 / 64) * (2048 / 64), 256, 0, stream>>>(
        w_o + (size_t)l * 2048 * 2048, Wt, 2048, 2048);
    k_gemm8_sk<<<256, 512, 0, stream>>>(o, 2048, Wt, 2048, 8, 512, Psk);
    k_red4_add<<<dim3(2, 2048), 256, 0, stream>>>(h, Psk, nullptr, 0);
    // post norm: dense text x, compacted audio xc
    k_rms<<<2048, 256, 0, stream>>>(h, ln_post + l * 2048, ln_audio_post + l * 2048, mask, x,
                                    xc, cpos);
    // text FFN: 8-phase fc, 8-phase split-K x4 proj
    k_transpose<<<(2048 / 64) * (8192 / 64), 256, 0, stream>>>(
        w_fc + (size_t)l * 2048 * 8192, Wt, 2048, 8192);
    k_gemm8_fc<<<256, 512, 0, stream>>>(x, Wt, t1);
    k_transpose<<<(8192 / 64) * (2048 / 64), 256, 0, stream>>>(
        w_proj + (size_t)l * 8192 * 2048, Wt, 8192, 2048);
    k_gemm8_sk<<<256, 512, 0, stream>>>(t1, 8192, Wt, 8192, 32, 2048, Psk);
    k_red4_add<<<dim3(2, 2048), 256, 0, stream>>>(h, Psk, mask, 2);
    // audio FFN (compacted rows ~3%; split-K 128^2 core)
    k_transpose<<<(2048 / 64) * (8192 / 64), 256, 0, stream>>>(
        w_afc + (size_t)l * 2048 * 8192, Wt, 2048, 8192);
    k_gemm_cs<<<dim3(64 * 4, 2), 256, 0, stream>>>(xc, 2048, Wt, 2048, 8, 64, Pafc, cnt);
    k_red4_silu<<<dim3(8, 256), 256, 0, stream>>>(Pafc, t1, cnt);
    k_transpose<<<(8192 / 64) * (2048 / 64), 256, 0, stream>>>(
        w_aproj + (size_t)l * 8192 * 2048, Wt, 8192, 2048);
    k_gemm_cs<<<dim3(16 * 8, 2), 256, 0, stream>>>(t1, 8192, Wt, 8192, 16, 16, Paprj, cnt);
    k_red8_scatter<<<dim3(2, 256), 256, 0, stream>>>(Paprj, h, cnt, cidx);
  }

  k_rms_final<<<2048, 256, 0, stream>>>(h, ln_f, out);
}

// Round 5
// 1145.974 us; speedup vs baseline: 1.7389x; 1.0011x over previous
//
#include <hip/hip_runtime.h>
#include <hip/hip_bf16.h>

typedef unsigned short u16;
typedef __attribute__((ext_vector_type(4))) float f32x4;
typedef __attribute__((ext_vector_type(8))) short bf16x8;
typedef __attribute__((ext_vector_type(8))) unsigned short u16x8;
typedef __attribute__((ext_vector_type(4))) unsigned short u16x4;

#define BM 128
#define BN 128
#define BK 64

__device__ __forceinline__ u16 f2bf(float f) {
  union { float f; unsigned u; } v; v.f = f;
  unsigned r = v.u + 0x7FFFu + ((v.u >> 16) & 1u);
  return (u16)(r >> 16);
}
__device__ __forceinline__ float bf2f(u16 v) {
  union { float f; unsigned u; } x; x.u = (unsigned)v << 16; return x.f;
}

__device__ __forceinline__ int xswz(int wg, int n) {  // bijective XCD swizzle, n%8==0
  return (wg & 7) * (n >> 3) + (wg >> 3);
}

// =================================================================== 8-phase 256^2 GEMM core
__device__ __forceinline__ void g8_stage_half(
    const u16* __restrict__ G, int ldg, int tile, int half, u16* ldsbase) {
  const int tid = threadIdx.x;
#pragma unroll
  for (int load = 0; load < 2; ++load) {
    int unit = load * 512 + tid;
    int row = unit >> 3, seg = unit & 7;
    __builtin_amdgcn_global_load_lds(
        (const __attribute__((address_space(1))) void*)(G + (size_t)(half * 128 + row) * ldg + tile * 64 + seg * 8),
        (__attribute__((address_space(3))) void*)(ldsbase + half * 8192 + load * 4096 + (tid >> 6) * 512),
        16, 0, 0);
  }
}

__device__ __forceinline__ void g8_core(
    const u16* __restrict__ A, int lda, const u16* __restrict__ Bt, int ldb,
    int NT, u16* lds, f32x4 acc[8][4]) {
  const int tid = threadIdx.x;
  const int lane = tid & 63;
  const int wid = tid >> 6;
  const int wr = wid >> 2, wc = wid & 3;
  const int lr = lane & 15, lk = (lane >> 4) * 8;

  u16* ldsA = lds;           // [buf][half][128][64]
  u16* ldsB = lds + 32768;

  g8_stage_half(A, lda, 0, 0, ldsA);
  g8_stage_half(A, lda, 0, 1, ldsA);
  g8_stage_half(Bt, ldb, 0, 0, ldsB);
  g8_stage_half(Bt, ldb, 0, 1, ldsB);
  if (NT > 1) {
    g8_stage_half(Bt, ldb, 1, 0, ldsB + 16384);
    g8_stage_half(Bt, ldb, 1, 1, ldsB + 16384);
  }
  asm volatile("s_waitcnt vmcnt(4)" ::: "memory");
  __builtin_amdgcn_s_barrier();
  __builtin_amdgcn_sched_barrier(0);

  for (int g = 0; g < NT; ++g) {
    const int buf = g & 1;
    const u16* cA = ldsA + buf * 16384 + wr * 8192;
    const u16* cB = ldsB + buf * 16384;
    bf16x8 bv[4][2];
#pragma unroll
    for (int p = 0; p < 4; ++p) {
      bf16x8 av[2][2];
      if (p == 0) {
#pragma unroll
        for (int n = 0; n < 4; ++n)
#pragma unroll
          for (int kk = 0; kk < 2; ++kk) {
            int rg = wc * 64 + n * 16 + lr;
            bv[n][kk] = *(const bf16x8*)&cB[(rg >> 7) * 8192 + (rg & 127) * 64 + kk * 32 + lk];
          }
      }
#pragma unroll
      for (int m2 = 0; m2 < 2; ++m2)
#pragma unroll
        for (int kk = 0; kk < 2; ++kk)
          av[m2][kk] = *(const bf16x8*)&cA[((p * 2 + m2) * 16 + lr) * 64 + kk * 32 + lk];

      if (p == 0 && g + 1 < NT) g8_stage_half(A, lda, g + 1, 0, ldsA + ((g + 1) & 1) * 16384);
      if (p == 1 && g + 1 < NT) g8_stage_half(A, lda, g + 1, 1, ldsA + ((g + 1) & 1) * 16384);
      if (p == 2 && g + 2 < NT) g8_stage_half(Bt, ldb, g + 2, 0, ldsB + buf * 16384);
      if (p == 3) {
        if (g + 2 < NT) {
          g8_stage_half(Bt, ldb, g + 2, 1, ldsB + buf * 16384);
          asm volatile("s_waitcnt vmcnt(4)" ::: "memory");
        } else if (g + 1 < NT) {
          asm volatile("s_waitcnt vmcnt(0)" ::: "memory");
        }
      }
      __builtin_amdgcn_s_barrier();
      asm volatile("s_waitcnt lgkmcnt(0)" ::: "memory");
      __builtin_amdgcn_sched_barrier(0);
      __builtin_amdgcn_s_setprio(1);
#pragma unroll
      for (int m2 = 0; m2 < 2; ++m2)
#pragma unroll
        for (int n = 0; n < 4; ++n)
#pragma unroll
          for (int kk = 0; kk < 2; ++kk)
            acc[p * 2 + m2][n] = __builtin_amdgcn_mfma_f32_16x16x32_bf16(
                av[m2][kk], bv[n][kk], acc[p * 2 + m2][n], 0, 0, 0);
      __builtin_amdgcn_s_setprio(0);
      __builtin_amdgcn_sched_barrier(0);
      __builtin_amdgcn_s_barrier();
    }
  }
}

__device__ __forceinline__ void g8_acc_zero(f32x4 acc[8][4]) {
#pragma unroll
  for (int m = 0; m < 8; ++m)
#pragma unroll
    for (int n = 0; n < 4; ++n)
      acc[m][n] = (f32x4){0.f, 0.f, 0.f, 0.f};
}

// qkv split-K x2 -> f32 partials [2][2048][4096]
__global__ __launch_bounds__(512, 2) void k_gemm8_qkv(
    const u16* __restrict__ A, const u16* __restrict__ Bt, float* __restrict__ Pq) {
  __shared__ u16 lds[65536];
  const int wg = xswz(blockIdx.x, 256);
  const int ks = wg >> 7, rem = wg & 127;
  const int tm = rem >> 4, tn = rem & 15;
  f32x4 acc[8][4];
  g8_acc_zero(acc);
  g8_core(A + (size_t)tm * 256 * 2048 + ks * 1024, 2048,
          Bt + (size_t)tn * 256 * 2048 + ks * 1024, 2048, 16, lds, acc);
  const int lane = threadIdx.x & 63, wid = threadIdx.x >> 6;
  const int wr = wid >> 2, wc = wid & 3;
  const int col = lane & 15, rb = (lane >> 4) * 4;
#pragma unroll
  for (int m = 0; m < 8; ++m)
#pragma unroll
    for (int n = 0; n < 4; ++n)
#pragma unroll
      for (int j = 0; j < 4; ++j) {
        int gm = tm * 256 + wr * 128 + m * 16 + rb + j;
        int gn = tn * 256 + wc * 64 + n * 16 + col;
        Pq[((size_t)ks * 2048 + gm) * 4096 + gn] = acc[m][n][j];
      }
}

// fc: full K, silu -> bf16 t1[2048][8192]
__global__ __launch_bounds__(512, 2) void k_gemm8_fc(
    const u16* __restrict__ A, const u16* __restrict__ Bt, u16* __restrict__ Cb) {
  __shared__ u16 lds[65536];
  const int wg = xswz(blockIdx.x, 256);
  const int tm = wg >> 5, tn = wg & 31;
  f32x4 acc[8][4];
  g8_acc_zero(acc);
  g8_core(A + (size_t)tm * 256 * 2048, 2048, Bt + (size_t)tn * 256 * 2048, 2048, 32, lds, acc);
  const int lane = threadIdx.x & 63, wid = threadIdx.x >> 6;
  const int wr = wid >> 2, wc = wid & 3;
  const int col = lane & 15, rb = (lane >> 4) * 4;
#pragma unroll
  for (int m = 0; m < 8; ++m)
#pragma unroll
    for (int n = 0; n < 4; ++n)
#pragma unroll
      for (int j = 0; j < 4; ++j) {
        int gm = tm * 256 + wr * 128 + m * 16 + rb + j;
        int gn = tn * 256 + wc * 64 + n * 16 + col;
        float v = acc[m][n][j];
        Cb[(size_t)gm * 8192 + gn] = f2bf(v / (1.f + __expf(-v)));
      }
}

// generic split-K x4 (M=N=2048) -> f32 partials [4][2048][2048]
__global__ __launch_bounds__(512, 2) void k_gemm8_sk(
    const u16* __restrict__ A, int lda, const u16* __restrict__ Bt, int ldb,
    int NT, int koff, float* __restrict__ Pp) {
  __shared__ u16 lds[65536];
  const int wg = xswz(blockIdx.x, 256);
  const int ks = wg >> 6, rem = wg & 63;
  const int tm = rem >> 3, tn = rem & 7;
  f32x4 acc[8][4];
  g8_acc_zero(acc);
  g8_core(A + (size_t)tm * 256 * lda + ks * koff, lda,
          Bt + (size_t)tn * 256 * ldb + ks * koff, ldb, NT, lds, acc);
  const int lane = threadIdx.x & 63, wid = threadIdx.x >> 6;
  const int wr = wid >> 2, wc = wid & 3;
  const int col = lane & 15, rb = (lane >> 4) * 4;
#pragma unroll
  for (int m = 0; m < 8; ++m)
#pragma unroll
    for (int n = 0; n < 4; ++n)
#pragma unroll
      for (int j = 0; j < 4; ++j) {
        int gm = tm * 256 + wr * 128 + m * 16 + rb + j;
        int gn = tn * 256 + wc * 64 + n * 16 + col;
        Pp[((size_t)ks * 2048 + gm) * 2048 + gn] = acc[m][n][j];
      }
}

// qkv reduce: sum 2 partials, bf16, scatter into Q/K/VT
__global__ __launch_bounds__(256) void k_red_qkv(
    const float* __restrict__ Pq, u16* __restrict__ Q, u16* __restrict__ Kb,
    u16* __restrict__ VT) {
  const int gm = blockIdx.y;
  const int c = blockIdx.x * 1024 + threadIdx.x * 4;
  const size_t i = (size_t)gm * 4096 + c;
  float4 a = *(const float4*)&Pq[i];
  float4 b2 = *(const float4*)&Pq[(size_t)2048 * 4096 + i];
  const int b = gm >> 10, s = gm & 1023;
  u16 v[4];
  v[0] = f2bf(a.x + b2.x); v[1] = f2bf(a.y + b2.y);
  v[2] = f2bf(a.z + b2.z); v[3] = f2bf(a.w + b2.w);
  const int d = c & 127;
  if (c < 2048) {
    int hh = c >> 7;
    *(u16x4*)&Q[((size_t)((b * 16 + hh) * 1024 + s)) * 128 + d] = *(u16x4*)v;
  } else if (c < 3072) {
    int kv = (c - 2048) >> 7;
    *(u16x4*)&Kb[((size_t)((b * 8 + kv) * 1024 + s)) * 128 + d] = *(u16x4*)v;
  } else {
    int kv = (c - 3072) >> 7;
#pragma unroll
    for (int j = 0; j < 4; ++j)
      VT[((size_t)((b * 8 + kv) * 128 + d + j)) * 1024 + s] = v[j];
  }
}

// =================================================================== 128^2 2-phase core (attention + audio)
__device__ __forceinline__ void acc_zero(f32x4 acc[4][4]) {
#pragma unroll
  for (int m = 0; m < 4; ++m)
#pragma unroll
    for (int n = 0; n < 4; ++n)
      acc[m][n] = (f32x4){0.f, 0.f, 0.f, 0.f};
}

__device__ __forceinline__ void gemm_core_db(
    const u16* __restrict__ A, int lda,
    const u16* __restrict__ Bt, int ldb,
    int ksteps, int amax, u16* sA, u16* sB, f32x4 acc[4][4]) {
  const int tid = threadIdx.x;
  const int wave = tid >> 6;
  const int lane = tid & 63;
  const int r = tid >> 3;
  const int ks = tid & 7;
  const int wm = (wave >> 1) * 64;
  const int wn = (wave & 1) * 64;
  const int lr = lane & 15;
  const int lk = (lane >> 4) * 8;

  auto stage = [&](int buf, int kt) {
    const int k0 = kt * BK;
    u16* dA = sA + buf * 8192 + wave * 512;
    u16* dB = sB + buf * 8192 + wave * 512;
#pragma unroll
    for (int i = 0; i < 4; ++i) {
      int ra = i * 32 + r; if (ra > amax) ra = amax;
      __builtin_amdgcn_global_load_lds(
          (const __attribute__((address_space(1))) void*)(A + (size_t)ra * lda + k0 + ks * 8),
          (__attribute__((address_space(3))) void*)(dA + i * 2048), 16, 0, 0);
      __builtin_amdgcn_global_load_lds(
          (const __attribute__((address_space(1))) void*)(Bt + (size_t)(i * 32 + r) * ldb + k0 + ks * 8),
          (__attribute__((address_space(3))) void*)(dB + i * 2048), 16, 0, 0);
    }
  };

  stage(0, 0);
  asm volatile("s_waitcnt vmcnt(0)" ::: "memory");
  __builtin_amdgcn_s_barrier();
  __builtin_amdgcn_sched_barrier(0);

  for (int kt = 0; kt < ksteps; ++kt) {
    const int cur = kt & 1;
    if (kt + 1 < ksteps) stage(cur ^ 1, kt + 1);
    const u16* cA = sA + cur * 8192;
    const u16* cB = sB + cur * 8192;
#pragma unroll
    for (int kk = 0; kk < BK; kk += 32) {
      bf16x8 av[4], bv[4];
#pragma unroll
      for (int m = 0; m < 4; ++m)
        av[m] = *(const bf16x8*)&cA[(wm + m * 16 + lr) * BK + kk + lk];
#pragma unroll
      for (int n = 0; n < 4; ++n)
        bv[n] = *(const bf16x8*)&cB[(wn + n * 16 + lr) * BK + kk + lk];
#pragma unroll
      for (int m = 0; m < 4; ++m)
#pragma unroll
        for (int n = 0; n < 4; ++n)
          acc[m][n] = __builtin_amdgcn_mfma_f32_16x16x32_bf16(av[m], bv[n], acc[m][n], 0, 0, 0);
    }
    asm volatile("s_waitcnt vmcnt(0)" ::: "memory");
    __builtin_amdgcn_s_barrier();
    __builtin_amdgcn_sched_barrier(0);
  }
}

// ------------------------------------------------------------- audio fc/proj (compacted split-K)
__global__ __launch_bounds__(256) void k_gemm_cs(
    const u16* __restrict__ A, int lda, const u16* __restrict__ Bt, int ldb,
    int ksteps, int ntn, float* __restrict__ Pp, const int* __restrict__ cnt) {
  const int Na = cnt[0];
  const int tm = blockIdx.y;
  if (tm * 128 >= Na) return;
  const int tn = blockIdx.x % ntn;
  const int ks = blockIdx.x / ntn;
  const int ldc = ntn * 128;
  const int k0 = ks * ksteps * BK;
  __shared__ u16 sA[2 * BM * BK], sB[2 * BN * BK];
  f32x4 acc[4][4];
  acc_zero(acc);
  gemm_core_db(A + (size_t)tm * 128 * lda + k0, lda, Bt + (size_t)tn * 128 * ldb + k0, ldb,
               ksteps, Na - 1 - tm * 128, sA, sB, acc);
  const int lane = threadIdx.x & 63, wave = threadIdx.x >> 6;
  const int wm = (wave >> 1) * 64, wn = (wave & 1) * 64;
  const int col = lane & 15, rb = (lane >> 4) * 4;
#pragma unroll
  for (int m = 0; m < 4; ++m)
#pragma unroll
    for (int n = 0; n < 4; ++n)
#pragma unroll
      for (int j = 0; j < 4; ++j) {
        int gm = tm * 128 + wm + m * 16 + rb + j;
        int gn = tn * 128 + wn + n * 16 + col;
        Pp[((size_t)ks * 256 + gm) * ldc + gn] = acc[m][n][j];
      }
}

__global__ __launch_bounds__(256) void k_red4_silu(
    const float* __restrict__ Pp, u16* __restrict__ t1, const int* __restrict__ cnt) {
  const int row = blockIdx.y;
  if (row >= cnt[0]) return;
  const int c = blockIdx.x * 1024 + threadIdx.x * 4;
  const size_t i = (size_t)row * 8192 + c;
  float4 s = *(const float4*)&Pp[i];
#pragma unroll
  for (int k = 1; k < 4; ++k) {
    float4 a = *(const float4*)&Pp[(size_t)k * 256 * 8192 + i];
    s.x += a.x; s.y += a.y; s.z += a.z; s.w += a.w;
  }
  u16x4 ov;
  const float* sf = (const float*)&s;
#pragma unroll
  for (int j = 0; j < 4; ++j) {
    float v = sf[j];
    ov[j] = f2bf(v / (1.f + __expf(-v)));
  }
  *(u16x4*)&t1[i] = ov;
}

// ------------------------------------------------------------- attention
// scores epilogue applies 1/sqrt(128) scale and writes bf16 S
__global__ __launch_bounds__(256) void k_scores(
    const u16* __restrict__ Q, const u16* __restrict__ Kb, u16* __restrict__ S) {
  const int bh = blockIdx.y;
  const int b = bh >> 4, hq = bh & 15, kv = hq >> 1;
  int i = blockIdx.x;
  int tm = 0;
  while ((tm + 1) * (tm + 2) / 2 <= i) ++tm;
  int tn = i - tm * (tm + 1) / 2;
  __shared__ u16 sA[2 * BM * BK], sB[2 * BN * BK];
  f32x4 acc[4][4];
  acc_zero(acc);
  const u16* Aq = Q + ((size_t)(b * 16 + hq) * 1024 + tm * 128) * 128;
  const u16* Bk = Kb + ((size_t)(b * 8 + kv) * 1024 + tn * 128) * 128;
  gemm_core_db(Aq, 128, Bk, 128, 2, 1 << 28, sA, sB, acc);
  u16* Sb = S + ((size_t)bh << 20);
  const int lane = threadIdx.x & 63, wave = threadIdx.x >> 6;
  const int wm = (wave >> 1) * 64, wn = (wave & 1) * 64;
  const int col = lane & 15, rb = (lane >> 4) * 4;
  const float scale = 0.08838834764831845f;
#pragma unroll
  for (int m = 0; m < 4; ++m)
#pragma unroll
    for (int n = 0; n < 4; ++n)
#pragma unroll
      for (int j = 0; j < 4; ++j)
        Sb[(size_t)(tm * 128 + wm + m * 16 + rb + j) * 1024 + tn * 128 + wn + n * 16 + col] =
            f2bf(acc[m][n][j] * scale);
}

__global__ __launch_bounds__(256) void k_softmax(const u16* __restrict__ S, u16* __restrict__ P) {
  const int q = blockIdx.x;
  const int zz = blockIdx.y;
  const int tid = threadIdx.x;
  const u16* row = S + ((size_t)zz << 20) + ((size_t)q << 10);
  u16* prow = P + ((size_t)zz << 20) + ((size_t)q << 10);
  u16x4 rv = *(const u16x4*)&row[tid * 4];
  float vals[4];
  float mx = -3.0e38f;
#pragma unroll
  for (int j = 0; j < 4; ++j) {
    int colj = tid * 4 + j;
    float t = (colj <= q) ? bf2f(rv[j]) : -3.0e38f;
    vals[j] = t;
    mx = fmaxf(mx, t);
  }
  __shared__ float red[8];
#pragma unroll
  for (int o = 32; o; o >>= 1) mx = fmaxf(mx, __shfl_xor(mx, o));
  if ((tid & 63) == 0) red[tid >> 6] = mx;
  __syncthreads();
  mx = fmaxf(fmaxf(red[0], red[1]), fmaxf(red[2], red[3]));
  float e[4];
  float sum = 0.f;
#pragma unroll
  for (int j = 0; j < 4; ++j) {
    int colj = tid * 4 + j;
    e[j] = (colj <= q) ? __expf(vals[j] - mx) : 0.f;
    sum += e[j];
  }
#pragma unroll
  for (int o = 32; o; o >>= 1) sum += __shfl_xor(sum, o);
  if ((tid & 63) == 0) red[4 + (tid >> 6)] = sum;
  __syncthreads();
  float inv = 1.f / (red[4] + red[5] + red[6] + red[7]);
  u16x4 ov;
#pragma unroll
  for (int j = 0; j < 4; ++j) ov[j] = f2bf(e[j] * inv);
  *(u16x4*)&prow[tid * 4] = ov;
}

__global__ __launch_bounds__(256) void k_pv(
    const u16* __restrict__ P, const u16* __restrict__ VT, u16* __restrict__ O) {
  const int bh = blockIdx.y;
  const int b = bh >> 4, hq = bh & 15, kv = hq >> 1;
  const int tm = blockIdx.x;
  __shared__ u16 sA[2 * BM * BK], sB[2 * BN * BK];
  f32x4 acc[4][4];
  acc_zero(acc);
  const u16* Ap = P + ((size_t)bh << 20) + (size_t)tm * 128 * 1024;
  const u16* Bv = VT + (size_t)(b * 8 + kv) * 128 * 1024;
  gemm_core_db(Ap, 1024, Bv, 1024, (tm + 1) * 2, 1 << 28, sA, sB, acc);
  const int lane = threadIdx.x & 63, wave = threadIdx.x >> 6;
  const int wm = (wave >> 1) * 64, wn = (wave & 1) * 64;
  const int col = lane & 15, rb = (lane >> 4) * 4;
#pragma unroll
  for (int m = 0; m < 4; ++m)
#pragma unroll
    for (int n = 0; n < 4; ++n)
#pragma unroll
      for (int j = 0; j < 4; ++j) {
        int s = tm * 128 + wm + m * 16 + rb + j;
        int d = wn + n * 16 + col;
        O[(size_t)(b * 1024 + s) * 2048 + hq * 128 + d] = f2bf(acc[m][n][j]);
      }
}

// ------------------------------------------------------------- transpose W[K,N]f32 -> Wt[N,K]bf16
// vectorized: float4 loads, u16x8 stores
__global__ __launch_bounds__(256) void k_transpose(
    const float* __restrict__ W, u16* __restrict__ Wt, int K, int N) {
  __shared__ float tile[64][68];
  const int nk = K >> 6;
  const int tk = blockIdx.x % nk;
  const int tn = blockIdx.x / nk;
  const int tid = threadIdx.x;
#pragma unroll
  for (int i = 0; i < 4; ++i) {
    int idx = i * 256 + tid;
    int r = idx >> 4, c4 = (idx & 15) * 4;
    float4 v = *(const float4*)&W[(size_t)(tk * 64 + r) * N + tn * 64 + c4];
    *(float4*)&tile[r][c4] = v;
  }
  __syncthreads();
#pragma unroll
  for (int i = 0; i < 2; ++i) {
    int idx = i * 256 + tid;
    int n = idx & 63, kg = idx >> 6;
    u16x8 ov;
#pragma unroll
    for (int j = 0; j < 8; ++j) ov[j] = f2bf(tile[kg * 8 + j][n]);
    *(u16x8*)&Wt[(size_t)(tn * 64 + n) * K + tk * 64 + kg * 8] = ov;
  }
}

// ------------------------------------------------------------- mask scan (1 block)
__global__ __launch_bounds__(256) void k_scan(
    const int* __restrict__ mask, int* __restrict__ cpos,
    int* __restrict__ cidx, int* __restrict__ cnt) {
  const int tid = threadIdx.x;
  const int lane = tid & 63, wid = tid >> 6;
  int m[8];
  int s = 0;
#pragma unroll
  for (int j = 0; j < 8; ++j) { m[j] = mask[tid * 8 + j]; s += m[j]; }
  int ps = s;
#pragma unroll
  for (int o = 1; o < 64; o <<= 1) {
    int t = __shfl_up(ps, o);
    if (lane >= o) ps += t;
  }
  __shared__ int wsum[4];
  if (lane == 63) wsum[wid] = ps;
  __syncthreads();
  int base = 0;
  for (int w = 0; w < wid; ++w) base += wsum[w];
  int run = base + ps - s;
#pragma unroll
  for (int j = 0; j < 8; ++j) {
    int row = tid * 8 + j;
    cpos[row] = run;
    if (m[j]) cidx[run] = row;
    run += m[j];
  }
  if (tid == 255) cnt[0] = run;
}

// ------------------------------------------------------------- RMS helpers
__device__ __forceinline__ float block_sum256(float v, float* red) {
  const int tid = threadIdx.x;
#pragma unroll
  for (int o = 32; o; o >>= 1) v += __shfl_xor(v, o);
  if ((tid & 63) == 0) red[tid >> 6] = v;
  __syncthreads();
  float r = red[0] + red[1] + red[2] + red[3];
  __syncthreads();
  return r;
}

// input norm (row-masked weight select) -- used once for layer 0
__global__ __launch_bounds__(256) void k_rms(
    const float* __restrict__ h, const float* __restrict__ wt, const float* __restrict__ wa,
    const int* __restrict__ mask, u16* __restrict__ out1) {
  const int row = blockIdx.x;
  const int tid = threadIdx.x;
  const float* hr = h + (size_t)row * 2048;
  float4 v0 = ((const float4*)hr)[tid * 2];
  float4 v1 = ((const float4*)hr)[tid * 2 + 1];
  const float* f0 = (const float*)&v0;
  const float* f1 = (const float*)&v1;
  float ss = 0.f;
#pragma unroll
  for (int j = 0; j < 4; ++j) ss += f0[j] * f0[j] + f1[j] * f1[j];
  __shared__ float red[4];
  ss = block_sum256(ss, red);
  const float inv = rsqrtf(ss * (1.0f / 2048.0f) + 1e-5f);
  const int c0 = tid * 8;
  const float* w = mask[row] ? wa : wt;
  u16x8 a;
#pragma unroll
  for (int j = 0; j < 8; ++j) {
    float hv = (j < 4 ? f0[j] : f1[j - 4]) * inv;
    a[j] = f2bf(hv * w[c0 + j]);
  }
  *(u16x8*)&out1[(size_t)row * 2048 + c0] = a;
}

// fused: h += sum4 o-proj partials ; post-norm -> x (text) + compacted xc (audio)
__global__ __launch_bounds__(256) void k_redrms_post(
    float* __restrict__ h, const float* __restrict__ Pp,
    const float* __restrict__ wt, const float* __restrict__ wa,
    const int* __restrict__ mask, u16* __restrict__ x, u16* __restrict__ xc,
    const int* __restrict__ cpos) {
  const int row = blockIdx.x, tid = threadIdx.x;
  const int c0 = tid * 8;
  const size_t base = (size_t)row * 2048 + c0;
  float4 a0 = *(const float4*)&h[base];
  float4 a1 = *(const float4*)&h[base + 4];
#pragma unroll
  for (int k = 0; k < 4; ++k) {
    const float* pk = Pp + (size_t)k * 2048 * 2048;
    float4 p0 = *(const float4*)&pk[base];
    float4 p1 = *(const float4*)&pk[base + 4];
    a0.x += p0.x; a0.y += p0.y; a0.z += p0.z; a0.w += p0.w;
    a1.x += p1.x; a1.y += p1.y; a1.z += p1.z; a1.w += p1.w;
  }
  *(float4*)&h[base] = a0;
  *(float4*)&h[base + 4] = a1;
  const float* f0 = (const float*)&a0;
  const float* f1 = (const float*)&a1;
  float ss = 0.f;
#pragma unroll
  for (int j = 0; j < 4; ++j) ss += f0[j] * f0[j] + f1[j] * f1[j];
  __shared__ float red[4];
  ss = block_sum256(ss, red);
  const float inv = rsqrtf(ss * (1.0f / 2048.0f) + 1e-5f);
  u16x8 xv;
#pragma unroll
  for (int j = 0; j < 8; ++j) {
    float hv = (j < 4 ? f0[j] : f1[j - 4]) * inv;
    xv[j] = f2bf(hv * wt[c0 + j]);
  }
  *(u16x8*)&x[base] = xv;
  if (mask[row]) {
    u16x8 av;
#pragma unroll
    for (int j = 0; j < 8; ++j) {
      float hv = (j < 4 ? f0[j] : f1[j - 4]) * inv;
      av[j] = f2bf(hv * wa[c0 + j]);
    }
    *(u16x8*)&xc[(size_t)cpos[row] * 2048 + c0] = av;
  }
}

// fused: h += (text? sum4 proj partials : sum8 audio-proj partials via cpos) ;
//        then next input-norm (select) -> x, or final ln_f -> outf
__global__ __launch_bounds__(256) void k_redrms_ffn(
    float* __restrict__ h, const float* __restrict__ Psk, const float* __restrict__ Pap,
    const float* __restrict__ wt, const float* __restrict__ wa,
    const float* __restrict__ wf, const int* __restrict__ mask,
    const int* __restrict__ cpos, u16* __restrict__ x, float* __restrict__ outf, int fin) {
  const int row = blockIdx.x, tid = threadIdx.x;
  const int c0 = tid * 8;
  const size_t base = (size_t)row * 2048 + c0;
  float4 a0 = *(const float4*)&h[base];
  float4 a1 = *(const float4*)&h[base + 4];
  if (mask[row] == 0) {
#pragma unroll
    for (int k = 0; k < 4; ++k) {
      const float* pk = Psk + (size_t)k * 2048 * 2048;
      float4 p0 = *(const float4*)&pk[base];
      float4 p1 = *(const float4*)&pk[base + 4];
      a0.x += p0.x; a0.y += p0.y; a0.z += p0.z; a0.w += p0.w;
      a1.x += p1.x; a1.y += p1.y; a1.z += p1.z; a1.w += p1.w;
    }
  } else {
    const size_t cb = (size_t)cpos[row] * 2048 + c0;
#pragma unroll
    for (int k = 0; k < 8; ++k) {
      const float* pk = Pap + (size_t)k * 256 * 2048;
      float4 p0 = *(const float4*)&pk[cb];
      float4 p1 = *(const float4*)&pk[cb + 4];
      a0.x += p0.x; a0.y += p0.y; a0.z += p0.z; a0.w += p0.w;
      a1.x += p1.x; a1.y += p1.y; a1.z += p1.z; a1.w += p1.w;
    }
  }
  if (!fin) {
    *(float4*)&h[base] = a0;
    *(float4*)&h[base + 4] = a1;
  }
  const float* f0 = (const float*)&a0;
  const float* f1 = (const float*)&a1;
  float ss = 0.f;
#pragma unroll
  for (int j = 0; j < 4; ++j) ss += f0[j] * f0[j] + f1[j] * f1[j];
  __shared__ float red[4];
  ss = block_sum256(ss, red);
  const float inv = rsqrtf(ss * (1.0f / 2048.0f) + 1e-5f);
  if (fin) {
    float4 o0, o1;
    float* p0 = (float*)&o0;
    float* p1 = (float*)&o1;
#pragma unroll
    for (int j = 0; j < 4; ++j) {
      p0[j] = f0[j] * inv * wf[c0 + j];
      p1[j] = f1[j] * inv * wf[c0 + 4 + j];
    }
    *(float4*)&outf[base] = o0;
    *(float4*)&outf[base + 4] = o1;
  } else {
    const float* w = mask[row] ? wa : wt;
    u16x8 xv;
#pragma unroll
    for (int j = 0; j < 8; ++j) {
      float hv = (j < 4 ? f0[j] : f1[j - 4]) * inv;
      xv[j] = f2bf(hv * w[c0 + j]);
    }
    *(u16x8*)&x[base] = xv;
  }
}

// ------------------------------------------------------------- embedding
__global__ __launch_bounds__(256) void k_embed(
    const int* __restrict__ ids, const float* __restrict__ vocab,
    const float* __restrict__ audio, float* __restrict__ h, int* __restrict__ mask) {
  const int t = blockIdx.x;
  const int tid = threadIdx.x;
  const int id = ids[t];
  const int am = (id > 31999) ? 1 : 0;
  if (tid == 0) mask[t] = am;
  float* hr = h + (size_t)t * 2048;
  if (!am) {
    const float4* src = (const float4*)(vocab + (size_t)id * 2048);
    for (int j = tid; j < 512; j += 256) ((float4*)hr)[j] = src[j];
  } else {
    const int aid = id - 32000;
    for (int j = tid; j < 512; j += 256) {
      float4 s = {0.f, 0.f, 0.f, 0.f};
#pragma unroll
      for (int c = 0; c < 8; ++c) {
        float4 a = ((const float4*)(audio + (size_t)(aid + c * 1026) * 2048))[j];
        s.x += a.x; s.y += a.y; s.z += a.z; s.w += a.w;
      }
      ((float4*)hr)[j] = s;
    }
  }
}

// ------------------------------------------------------------- host launch
extern "C" void kernel_launch(void* const* d_in, const int* in_sizes, int n_in,
                              void* d_out, int out_size, void* d_ws, size_t ws_size,
                              hipStream_t stream) {
  const int* ids = (const int*)d_in[0];
  const float* vocab = (const float*)d_in[1];
  const float* audio = (const float*)d_in[2];
  const float* ln_in = (const float*)d_in[3];
  const float* ln_audio_in = (const float*)d_in[4];
  const float* ln_post = (const float*)d_in[5];
  const float* ln_audio_post = (const float*)d_in[6];
  const float* w_qkv = (const float*)d_in[7];
  const float* w_o = (const float*)d_in[8];
  const float* w_fc = (const float*)d_in[9];
  const float* w_proj = (const float*)d_in[10];
  const float* w_afc = (const float*)d_in[11];
  const float* w_aproj = (const float*)d_in[12];
  const float* ln_f = (const float*)d_in[13];
  float* out = (float*)d_out;

  char* p = (char*)d_ws;
  auto alloc = [&](size_t bytes) {
    char* r = p;
    p += (bytes + 255) & ~(size_t)255;
    return r;
  };
  float* h   = (float*)alloc((size_t)2048 * 2048 * 4);
  u16* x     = (u16*)alloc((size_t)2048 * 2048 * 2);
  u16* xc    = (u16*)alloc((size_t)2048 * 2048 * 2);
  u16* o     = (u16*)alloc((size_t)2048 * 2048 * 2);
  int* mask  = (int*)alloc((size_t)2048 * 4);
  int* cpos  = (int*)alloc((size_t)2048 * 4);
  int* cidx  = (int*)alloc((size_t)2048 * 4);
  int* cnt   = (int*)alloc((size_t)64 * 4);
  u16* Wt    = (u16*)alloc((size_t)8192 * 2048 * 2);
  u16* Q     = (u16*)alloc((size_t)2 * 16 * 1024 * 128 * 2);
  u16* Kb    = (u16*)alloc((size_t)2 * 8 * 1024 * 128 * 2);
  u16* VT    = (u16*)alloc((size_t)2 * 8 * 1024 * 128 * 2);
  char* A    = alloc((size_t)32 * 1024 * 1024 * 4);          // 134 MB multi-use region
  u16* P     = (u16*)alloc((size_t)32 * 1024 * 1024 * 2);    // 67 MB attn probs
  u16* t1    = (u16*)alloc((size_t)2048 * 8192 * 2);
  // Region A aliases (lifetimes disjoint in stream order):
  float* Pq    = (float*)A;                          // [2][2048][4096] qkv partials
  u16*   Sb    = (u16*)A;                            // [32][1024][1024] bf16 scores
  float* Psk   = (float*)A;                          // [4][2048][2048] o/proj partials
  float* Pafc  = (float*)(A + (size_t)67108864 + 4194304);   // [4][256][8192]
  float* Paprj = (float*)(A + (size_t)100663296 + 8388608);  // [8][256][2048]
  (void)ws_size; (void)in_sizes; (void)n_in; (void)out_size;

  k_embed<<<2048, 256, 0, stream>>>(ids, vocab, audio, h, mask);
  k_scan<<<1, 256, 0, stream>>>(mask, cpos, cidx, cnt);
  // layer-0 input norm
  k_rms<<<2048, 256, 0, stream>>>(h, ln_in, ln_audio_in, mask, x);

  for (int l = 0; l < 2; ++l) {
    // qkv: 8-phase split-K x2 -> partials -> scatter reduce
    k_transpose<<<(2048 / 64) * (4096 / 64), 256, 0, stream>>>(
        w_qkv + (size_t)l * 2048 * 4096, Wt, 2048, 4096);
    k_gemm8_qkv<<<256, 512, 0, stream>>>(x, Wt, Pq);
    k_red_qkv<<<dim3(4, 2048), 256, 0, stream>>>(Pq, Q, Kb, VT);
    // attention (bf16 scores)
    k_scores<<<dim3(36, 32), 256, 0, stream>>>(Q, Kb, Sb);
    k_softmax<<<dim3(1024, 32), 256, 0, stream>>>(Sb, P);
    k_pv<<<dim3(8, 32), 256, 0, stream>>>(P, VT, o);
    // o-proj split-K x4 -> fused reduce + residual + post-norm
    k_transpose<<<(2048 / 64) * (2048 / 64), 256, 0, stream>>>(
        w_o + (size_t)l * 2048 * 2048, Wt, 2048, 2048);
    k_gemm8_sk<<<256, 512, 0, stream>>>(o, 2048, Wt, 2048, 8, 512, Psk);
    k_redrms_post<<<2048, 256, 0, stream>>>(h, Psk, ln_post + l * 2048,
                                            ln_audio_post + l * 2048, mask, x, xc, cpos);
    // text FFN
    k_transpose<<<(2048 / 64) * (8192 / 64), 256, 0, stream>>>(
        w_fc + (size_t)l * 2048 * 8192, Wt, 2048, 8192);
    k_gemm8_fc<<<256, 512, 0, stream>>>(x, Wt, t1);
    k_transpose<<<(8192 / 64) * (2048 / 64), 256, 0, stream>>>(
        w_proj + (size_t)l * 8192 * 2048, Wt, 8192, 2048);
    k_gemm8_sk<<<256, 512, 0, stream>>>(t1, 8192, Wt, 8192, 32, 2048, Psk);
    // audio FFN (compacted, split-K 128^2 core)
    k_transpose<<<(2048 / 64) * (8192 / 64), 256, 0, stream>>>(
        w_afc + (size_t)l * 2048 * 8192, Wt, 2048, 8192);
    k_gemm_cs<<<dim3(64 * 4, 2), 256, 0, stream>>>(xc, 2048, Wt, 2048, 8, 64, Pafc, cnt);
    k_red4_silu<<<dim3(8, 256), 256, 0, stream>>>(Pafc, t1, cnt);
    k_transpose<<<(8192 / 64) * (2048 / 64), 256, 0, stream>>>(
        w_aproj + (size_t)l * 8192 * 2048, Wt, 8192, 2048);
    k_gemm_cs<<<dim3(16 * 8, 2), 256, 0, stream>>>(t1, 8192, Wt, 8192, 16, 16, Paprj, cnt);
    // fused: both-path residual add + (next input-norm | final ln_f)
    if (l == 0)
      k_redrms_ffn<<<2048, 256, 0, stream>>>(h, Psk, Paprj, ln_in + 2048,
                                             ln_audio_in + 2048, nullptr, mask, cpos, x,
                                             nullptr, 0);
    else
      k_redrms_ffn<<<2048, 256, 0, stream>>>(h, Psk, Paprj, nullptr, nullptr, ln_f, mask,
                                             cpos, nullptr, out, 1);
  }
}

// Round 6
// 1048.147 us; speedup vs baseline: 1.9012x; 1.0933x over previous
//
#include <hip/hip_runtime.h>
#include <hip/hip_bf16.h>

typedef unsigned short u16;
typedef __attribute__((ext_vector_type(4))) float f32x4;
typedef __attribute__((ext_vector_type(8))) short bf16x8;
typedef __attribute__((ext_vector_type(8))) unsigned short u16x8;
typedef __attribute__((ext_vector_type(4))) unsigned short u16x4;

#define BM 128
#define BN 128
#define BK 64

__device__ __forceinline__ u16 f2bf(float f) {
  union { float f; unsigned u; } v; v.f = f;
  unsigned r = v.u + 0x7FFFu + ((v.u >> 16) & 1u);
  return (u16)(r >> 16);
}
__device__ __forceinline__ float bf2f(u16 v) {
  union { float f; unsigned u; } x; x.u = (unsigned)v << 16; return x.f;
}

__device__ __forceinline__ int xswz(int wg, int n) {  // bijective XCD swizzle, n%8==0
  return (wg & 7) * (n >> 3) + (wg >> 3);
}

// =================================================================== 8-phase 256^2 GEMM core
// T2 LDS swizzle (rule #21: linear gload_lds dest + inverse-swizzled global SOURCE
// + swizzled READ). Swizzle: 16B slot s at row r lives at LDS slot s ^ (r&7).
__device__ __forceinline__ void g8_stage_half(
    const u16* __restrict__ G, int ldg, int tile, int half, u16* ldsbase) {
  const int tid = threadIdx.x;
#pragma unroll
  for (int load = 0; load < 2; ++load) {
    int unit = load * 512 + tid;
    int row = unit >> 3;
    int seg = (unit & 7) ^ ((unit >> 3) & 7);  // pre-swizzled source segment
    __builtin_amdgcn_global_load_lds(
        (const __attribute__((address_space(1))) void*)(G + (size_t)(half * 128 + row) * ldg + tile * 64 + seg * 8),
        (__attribute__((address_space(3))) void*)(ldsbase + half * 8192 + load * 4096 + (tid >> 6) * 512),
        16, 0, 0);
  }
}

__device__ __forceinline__ void g8_core(
    const u16* __restrict__ A, int lda, const u16* __restrict__ Bt, int ldb,
    int NT, u16* lds, f32x4 acc[8][4]) {
  const int tid = threadIdx.x;
  const int lane = tid & 63;
  const int wid = tid >> 6;
  const int wr = wid >> 2, wc = wid & 3;
  const int lr = lane & 15;
  const int lk4 = lane >> 4;          // 0..3 -> 16B slot within 64B group
  const int sw = lane & 7;            // read-side swizzle factor (= row&7)
  const int off0 = ((lk4 ^ sw) * 8);          // kk=0 element offset
  const int off1 = (((4 + lk4) ^ sw) * 8);    // kk=1 element offset

  u16* ldsA = lds;           // [buf][half][128][64]
  u16* ldsB = lds + 32768;

  g8_stage_half(A, lda, 0, 0, ldsA);
  g8_stage_half(A, lda, 0, 1, ldsA);
  g8_stage_half(Bt, ldb, 0, 0, ldsB);
  g8_stage_half(Bt, ldb, 0, 1, ldsB);
  if (NT > 1) {
    g8_stage_half(Bt, ldb, 1, 0, ldsB + 16384);
    g8_stage_half(Bt, ldb, 1, 1, ldsB + 16384);
  }
  asm volatile("s_waitcnt vmcnt(4)" ::: "memory");
  __builtin_amdgcn_s_barrier();
  __builtin_amdgcn_sched_barrier(0);

  for (int g = 0; g < NT; ++g) {
    const int buf = g & 1;
    const u16* cA = ldsA + buf * 16384 + wr * 8192;
    const u16* cB = ldsB + buf * 16384;
    bf16x8 bv[4][2];
#pragma unroll
    for (int p = 0; p < 4; ++p) {
      bf16x8 av[2][2];
      if (p == 0) {
#pragma unroll
        for (int n = 0; n < 4; ++n) {
          int rg = wc * 64 + n * 16 + lr;
          const u16* rbase = &cB[(rg >> 7) * 8192 + (rg & 127) * 64];
          bv[n][0] = *(const bf16x8*)&rbase[off0];
          bv[n][1] = *(const bf16x8*)&rbase[off1];
        }
      }
#pragma unroll
      for (int m2 = 0; m2 < 2; ++m2) {
        const u16* rbase = &cA[((p * 2 + m2) * 16 + lr) * 64];
        av[m2][0] = *(const bf16x8*)&rbase[off0];
        av[m2][1] = *(const bf16x8*)&rbase[off1];
      }

      if (p == 0 && g + 1 < NT) g8_stage_half(A, lda, g + 1, 0, ldsA + ((g + 1) & 1) * 16384);
      if (p == 1 && g + 1 < NT) g8_stage_half(A, lda, g + 1, 1, ldsA + ((g + 1) & 1) * 16384);
      if (p == 2 && g + 2 < NT) g8_stage_half(Bt, ldb, g + 2, 0, ldsB + buf * 16384);
      if (p == 3) {
        if (g + 2 < NT) {
          g8_stage_half(Bt, ldb, g + 2, 1, ldsB + buf * 16384);
          asm volatile("s_waitcnt vmcnt(4)" ::: "memory");
        } else if (g + 1 < NT) {
          asm volatile("s_waitcnt vmcnt(0)" ::: "memory");
        }
      }
      __builtin_amdgcn_s_barrier();
      asm volatile("s_waitcnt lgkmcnt(0)" ::: "memory");
      __builtin_amdgcn_sched_barrier(0);
      __builtin_amdgcn_s_setprio(1);
#pragma unroll
      for (int m2 = 0; m2 < 2; ++m2)
#pragma unroll
        for (int n = 0; n < 4; ++n)
#pragma unroll
          for (int kk = 0; kk < 2; ++kk)
            acc[p * 2 + m2][n] = __builtin_amdgcn_mfma_f32_16x16x32_bf16(
                av[m2][kk], bv[n][kk], acc[p * 2 + m2][n], 0, 0, 0);
      __builtin_amdgcn_s_setprio(0);
      __builtin_amdgcn_sched_barrier(0);
      __builtin_amdgcn_s_barrier();
    }
  }
}

__device__ __forceinline__ void g8_acc_zero(f32x4 acc[8][4]) {
#pragma unroll
  for (int m = 0; m < 8; ++m)
#pragma unroll
    for (int n = 0; n < 4; ++n)
      acc[m][n] = (f32x4){0.f, 0.f, 0.f, 0.f};
}

// qkv split-K x2 -> f32 partials [2][2048][4096]
__global__ __launch_bounds__(512, 2) void k_gemm8_qkv(
    const u16* __restrict__ A, const u16* __restrict__ Bt, float* __restrict__ Pq) {
  __shared__ u16 lds[65536];
  const int wg = xswz(blockIdx.x, 256);
  const int ks = wg >> 7, rem = wg & 127;
  const int tm = rem >> 4, tn = rem & 15;
  f32x4 acc[8][4];
  g8_acc_zero(acc);
  g8_core(A + (size_t)tm * 256 * 2048 + ks * 1024, 2048,
          Bt + (size_t)tn * 256 * 2048 + ks * 1024, 2048, 16, lds, acc);
  const int lane = threadIdx.x & 63, wid = threadIdx.x >> 6;
  const int wr = wid >> 2, wc = wid & 3;
  const int col = lane & 15, rb = (lane >> 4) * 4;
#pragma unroll
  for (int m = 0; m < 8; ++m)
#pragma unroll
    for (int n = 0; n < 4; ++n)
#pragma unroll
      for (int j = 0; j < 4; ++j) {
        int gm = tm * 256 + wr * 128 + m * 16 + rb + j;
        int gn = tn * 256 + wc * 64 + n * 16 + col;
        Pq[((size_t)ks * 2048 + gm) * 4096 + gn] = acc[m][n][j];
      }
}

// fc: full K, silu -> bf16 t1[2048][8192]
__global__ __launch_bounds__(512, 2) void k_gemm8_fc(
    const u16* __restrict__ A, const u16* __restrict__ Bt, u16* __restrict__ Cb) {
  __shared__ u16 lds[65536];
  const int wg = xswz(blockIdx.x, 256);
  const int tm = wg >> 5, tn = wg & 31;
  f32x4 acc[8][4];
  g8_acc_zero(acc);
  g8_core(A + (size_t)tm * 256 * 2048, 2048, Bt + (size_t)tn * 256 * 2048, 2048, 32, lds, acc);
  const int lane = threadIdx.x & 63, wid = threadIdx.x >> 6;
  const int wr = wid >> 2, wc = wid & 3;
  const int col = lane & 15, rb = (lane >> 4) * 4;
#pragma unroll
  for (int m = 0; m < 8; ++m)
#pragma unroll
    for (int n = 0; n < 4; ++n)
#pragma unroll
      for (int j = 0; j < 4; ++j) {
        int gm = tm * 256 + wr * 128 + m * 16 + rb + j;
        int gn = tn * 256 + wc * 64 + n * 16 + col;
        float v = acc[m][n][j];
        Cb[(size_t)gm * 8192 + gn] = f2bf(v / (1.f + __expf(-v)));
      }
}

// generic split-K x4 (M=N=2048) -> f32 partials [4][2048][2048]
__global__ __launch_bounds__(512, 2) void k_gemm8_sk(
    const u16* __restrict__ A, int lda, const u16* __restrict__ Bt, int ldb,
    int NT, int koff, float* __restrict__ Pp) {
  __shared__ u16 lds[65536];
  const int wg = xswz(blockIdx.x, 256);
  const int ks = wg >> 6, rem = wg & 63;
  const int tm = rem >> 3, tn = rem & 7;
  f32x4 acc[8][4];
  g8_acc_zero(acc);
  g8_core(A + (size_t)tm * 256 * lda + ks * koff, lda,
          Bt + (size_t)tn * 256 * ldb + ks * koff, ldb, NT, lds, acc);
  const int lane = threadIdx.x & 63, wid = threadIdx.x >> 6;
  const int wr = wid >> 2, wc = wid & 3;
  const int col = lane & 15, rb = (lane >> 4) * 4;
#pragma unroll
  for (int m = 0; m < 8; ++m)
#pragma unroll
    for (int n = 0; n < 4; ++n)
#pragma unroll
      for (int j = 0; j < 4; ++j) {
        int gm = tm * 256 + wr * 128 + m * 16 + rb + j;
        int gn = tn * 256 + wc * 64 + n * 16 + col;
        Pp[((size_t)ks * 2048 + gm) * 2048 + gn] = acc[m][n][j];
      }
}

// qkv reduce: sum 2 partials, bf16, scatter into Q/K/VT
__global__ __launch_bounds__(256) void k_red_qkv(
    const float* __restrict__ Pq, u16* __restrict__ Q, u16* __restrict__ Kb,
    u16* __restrict__ VT) {
  const int gm = blockIdx.y;
  const int c = blockIdx.x * 1024 + threadIdx.x * 4;
  const size_t i = (size_t)gm * 4096 + c;
  float4 a = *(const float4*)&Pq[i];
  float4 b2 = *(const float4*)&Pq[(size_t)2048 * 4096 + i];
  const int b = gm >> 10, s = gm & 1023;
  u16 v[4];
  v[0] = f2bf(a.x + b2.x); v[1] = f2bf(a.y + b2.y);
  v[2] = f2bf(a.z + b2.z); v[3] = f2bf(a.w + b2.w);
  const int d = c & 127;
  if (c < 2048) {
    int hh = c >> 7;
    *(u16x4*)&Q[((size_t)((b * 16 + hh) * 1024 + s)) * 128 + d] = *(u16x4*)v;
  } else if (c < 3072) {
    int kv = (c - 2048) >> 7;
    *(u16x4*)&Kb[((size_t)((b * 8 + kv) * 1024 + s)) * 128 + d] = *(u16x4*)v;
  } else {
    int kv = (c - 3072) >> 7;
#pragma unroll
    for (int j = 0; j < 4; ++j)
      VT[((size_t)((b * 8 + kv) * 128 + d + j)) * 1024 + s] = v[j];
  }
}

// =================================================================== 128^2 2-phase core (attention + audio)
// Same T2 swizzle convention as g8 (stage source seg ^ destrow&7, read slot ^ lr&7).
__device__ __forceinline__ void acc_zero(f32x4 acc[4][4]) {
#pragma unroll
  for (int m = 0; m < 4; ++m)
#pragma unroll
    for (int n = 0; n < 4; ++n)
      acc[m][n] = (f32x4){0.f, 0.f, 0.f, 0.f};
}

__device__ __forceinline__ void gemm_core_db(
    const u16* __restrict__ A, int lda,
    const u16* __restrict__ Bt, int ldb,
    int ksteps, int amax, u16* sA, u16* sB, f32x4 acc[4][4]) {
  const int tid = threadIdx.x;
  const int wave = tid >> 6;
  const int lane = tid & 63;
  const int r = tid >> 3;
  const int ksw = (tid & 7) ^ ((tid >> 3) & 7);  // pre-swizzled source segment
  const int wm = (wave >> 1) * 64;
  const int wn = (wave & 1) * 64;
  const int lr = lane & 15;
  const int lk4 = lane >> 4;
  const int sw = lane & 7;
  const int off0 = ((lk4 ^ sw) * 8);
  const int off1 = (((4 + lk4) ^ sw) * 8);

  auto stage = [&](int buf, int kt) {
    const int k0 = kt * BK;
    u16* dA = sA + buf * 8192 + wave * 512;
    u16* dB = sB + buf * 8192 + wave * 512;
#pragma unroll
    for (int i = 0; i < 4; ++i) {
      int ra = i * 32 + r; if (ra > amax) ra = amax;
      __builtin_amdgcn_global_load_lds(
          (const __attribute__((address_space(1))) void*)(A + (size_t)ra * lda + k0 + ksw * 8),
          (__attribute__((address_space(3))) void*)(dA + i * 2048), 16, 0, 0);
      __builtin_amdgcn_global_load_lds(
          (const __attribute__((address_space(1))) void*)(Bt + (size_t)(i * 32 + r) * ldb + k0 + ksw * 8),
          (__attribute__((address_space(3))) void*)(dB + i * 2048), 16, 0, 0);
    }
  };

  stage(0, 0);
  asm volatile("s_waitcnt vmcnt(0)" ::: "memory");
  __builtin_amdgcn_s_barrier();
  __builtin_amdgcn_sched_barrier(0);

  for (int kt = 0; kt < ksteps; ++kt) {
    const int cur = kt & 1;
    if (kt + 1 < ksteps) stage(cur ^ 1, kt + 1);
    const u16* cA = sA + cur * 8192;
    const u16* cB = sB + cur * 8192;
#pragma unroll
    for (int kk = 0; kk < 2; ++kk) {
      const int off = kk ? off1 : off0;
      bf16x8 av[4], bv[4];
#pragma unroll
      for (int m = 0; m < 4; ++m)
        av[m] = *(const bf16x8*)&cA[(wm + m * 16 + lr) * BK + off];
#pragma unroll
      for (int n = 0; n < 4; ++n)
        bv[n] = *(const bf16x8*)&cB[(wn + n * 16 + lr) * BK + off];
#pragma unroll
      for (int m = 0; m < 4; ++m)
#pragma unroll
        for (int n = 0; n < 4; ++n)
          acc[m][n] = __builtin_amdgcn_mfma_f32_16x16x32_bf16(av[m], bv[n], acc[m][n], 0, 0, 0);
    }
    asm volatile("s_waitcnt vmcnt(0)" ::: "memory");
    __builtin_amdgcn_s_barrier();
    __builtin_amdgcn_sched_barrier(0);
  }
}

// ------------------------------------------------------------- audio fc/proj (compacted split-K)
__global__ __launch_bounds__(256) void k_gemm_cs(
    const u16* __restrict__ A, int lda, const u16* __restrict__ Bt, int ldb,
    int ksteps, int ntn, float* __restrict__ Pp, const int* __restrict__ cnt) {
  const int Na = cnt[0];
  const int tm = blockIdx.y;
  if (tm * 128 >= Na) return;
  const int tn = blockIdx.x % ntn;
  const int ks = blockIdx.x / ntn;
  const int ldc = ntn * 128;
  const int k0 = ks * ksteps * BK;
  __shared__ u16 sA[2 * BM * BK], sB[2 * BN * BK];
  f32x4 acc[4][4];
  acc_zero(acc);
  gemm_core_db(A + (size_t)tm * 128 * lda + k0, lda, Bt + (size_t)tn * 128 * ldb + k0, ldb,
               ksteps, Na - 1 - tm * 128, sA, sB, acc);
  const int lane = threadIdx.x & 63, wave = threadIdx.x >> 6;
  const int wm = (wave >> 1) * 64, wn = (wave & 1) * 64;
  const int col = lane & 15, rb = (lane >> 4) * 4;
#pragma unroll
  for (int m = 0; m < 4; ++m)
#pragma unroll
    for (int n = 0; n < 4; ++n)
#pragma unroll
      for (int j = 0; j < 4; ++j) {
        int gm = tm * 128 + wm + m * 16 + rb + j;
        int gn = tn * 128 + wn + n * 16 + col;
        Pp[((size_t)ks * 256 + gm) * ldc + gn] = acc[m][n][j];
      }
}

__global__ __launch_bounds__(256) void k_red4_silu(
    const float* __restrict__ Pp, u16* __restrict__ t1, const int* __restrict__ cnt) {
  const int row = blockIdx.y;
  if (row >= cnt[0]) return;
  const int c = blockIdx.x * 1024 + threadIdx.x * 4;
  const size_t i = (size_t)row * 8192 + c;
  float4 s = *(const float4*)&Pp[i];
#pragma unroll
  for (int k = 1; k < 4; ++k) {
    float4 a = *(const float4*)&Pp[(size_t)k * 256 * 8192 + i];
    s.x += a.x; s.y += a.y; s.z += a.z; s.w += a.w;
  }
  u16x4 ov;
  const float* sf = (const float*)&s;
#pragma unroll
  for (int j = 0; j < 4; ++j) {
    float v = sf[j];
    ov[j] = f2bf(v / (1.f + __expf(-v)));
  }
  *(u16x4*)&t1[i] = ov;
}

// ------------------------------------------------------------- attention
// scores epilogue applies 1/sqrt(128) scale and writes bf16 S
__global__ __launch_bounds__(256) void k_scores(
    const u16* __restrict__ Q, const u16* __restrict__ Kb, u16* __restrict__ S) {
  const int bh = blockIdx.y;
  const int b = bh >> 4, hq = bh & 15, kv = hq >> 1;
  int i = blockIdx.x;
  int tm = 0;
  while ((tm + 1) * (tm + 2) / 2 <= i) ++tm;
  int tn = i - tm * (tm + 1) / 2;
  __shared__ u16 sA[2 * BM * BK], sB[2 * BN * BK];
  f32x4 acc[4][4];
  acc_zero(acc);
  const u16* Aq = Q + ((size_t)(b * 16 + hq) * 1024 + tm * 128) * 128;
  const u16* Bk = Kb + ((size_t)(b * 8 + kv) * 1024 + tn * 128) * 128;
  gemm_core_db(Aq, 128, Bk, 128, 2, 1 << 28, sA, sB, acc);
  u16* Sb = S + ((size_t)bh << 20);
  const int lane = threadIdx.x & 63, wave = threadIdx.x >> 6;
  const int wm = (wave >> 1) * 64, wn = (wave & 1) * 64;
  const int col = lane & 15, rb = (lane >> 4) * 4;
  const float scale = 0.08838834764831845f;
#pragma unroll
  for (int m = 0; m < 4; ++m)
#pragma unroll
    for (int n = 0; n < 4; ++n)
#pragma unroll
      for (int j = 0; j < 4; ++j)
        Sb[(size_t)(tm * 128 + wm + m * 16 + rb + j) * 1024 + tn * 128 + wn + n * 16 + col] =
            f2bf(acc[m][n][j] * scale);
}

__global__ __launch_bounds__(256) void k_softmax(const u16* __restrict__ S, u16* __restrict__ P) {
  const int q = blockIdx.x;
  const int zz = blockIdx.y;
  const int tid = threadIdx.x;
  const u16* row = S + ((size_t)zz << 20) + ((size_t)q << 10);
  u16* prow = P + ((size_t)zz << 20) + ((size_t)q << 10);
  u16x4 rv = *(const u16x4*)&row[tid * 4];
  float vals[4];
  float mx = -3.0e38f;
#pragma unroll
  for (int j = 0; j < 4; ++j) {
    int colj = tid * 4 + j;
    float t = (colj <= q) ? bf2f(rv[j]) : -3.0e38f;
    vals[j] = t;
    mx = fmaxf(mx, t);
  }
  __shared__ float red[8];
#pragma unroll
  for (int o = 32; o; o >>= 1) mx = fmaxf(mx, __shfl_xor(mx, o));
  if ((tid & 63) == 0) red[tid >> 6] = mx;
  __syncthreads();
  mx = fmaxf(fmaxf(red[0], red[1]), fmaxf(red[2], red[3]));
  float e[4];
  float sum = 0.f;
#pragma unroll
  for (int j = 0; j < 4; ++j) {
    int colj = tid * 4 + j;
    e[j] = (colj <= q) ? __expf(vals[j] - mx) : 0.f;
    sum += e[j];
  }
#pragma unroll
  for (int o = 32; o; o >>= 1) sum += __shfl_xor(sum, o);
  if ((tid & 63) == 0) red[4 + (tid >> 6)] = sum;
  __syncthreads();
  float inv = 1.f / (red[4] + red[5] + red[6] + red[7]);
  u16x4 ov;
#pragma unroll
  for (int j = 0; j < 4; ++j) ov[j] = f2bf(e[j] * inv);
  *(u16x4*)&prow[tid * 4] = ov;
}

__global__ __launch_bounds__(256) void k_pv(
    const u16* __restrict__ P, const u16* __restrict__ VT, u16* __restrict__ O) {
  const int bh = blockIdx.y;
  const int b = bh >> 4, hq = bh & 15, kv = hq >> 1;
  const int tm = blockIdx.x;
  __shared__ u16 sA[2 * BM * BK], sB[2 * BN * BK];
  f32x4 acc[4][4];
  acc_zero(acc);
  const u16* Ap = P + ((size_t)bh << 20) + (size_t)tm * 128 * 1024;
  const u16* Bv = VT + (size_t)(b * 8 + kv) * 128 * 1024;
  gemm_core_db(Ap, 1024, Bv, 1024, (tm + 1) * 2, 1 << 28, sA, sB, acc);
  const int lane = threadIdx.x & 63, wave = threadIdx.x >> 6;
  const int wm = (wave >> 1) * 64, wn = (wave & 1) * 64;
  const int col = lane & 15, rb = (lane >> 4) * 4;
#pragma unroll
  for (int m = 0; m < 4; ++m)
#pragma unroll
    for (int n = 0; n < 4; ++n)
#pragma unroll
      for (int j = 0; j < 4; ++j) {
        int s = tm * 128 + wm + m * 16 + rb + j;
        int d = wn + n * 16 + col;
        O[(size_t)(b * 1024 + s) * 2048 + hq * 128 + d] = f2bf(acc[m][n][j]);
      }
}

// ------------------------------------------------------------- transpose W[K,N]f32 -> Wt[N,K]bf16
// vectorized: float4 loads, u16x8 stores
__global__ __launch_bounds__(256) void k_transpose(
    const float* __restrict__ W, u16* __restrict__ Wt, int K, int N) {
  __shared__ float tile[64][68];
  const int nk = K >> 6;
  const int tk = blockIdx.x % nk;
  const int tn = blockIdx.x / nk;
  const int tid = threadIdx.x;
#pragma unroll
  for (int i = 0; i < 4; ++i) {
    int idx = i * 256 + tid;
    int r = idx >> 4, c4 = (idx & 15) * 4;
    float4 v = *(const float4*)&W[(size_t)(tk * 64 + r) * N + tn * 64 + c4];
    *(float4*)&tile[r][c4] = v;
  }
  __syncthreads();
#pragma unroll
  for (int i = 0; i < 2; ++i) {
    int idx = i * 256 + tid;
    int n = idx & 63, kg = idx >> 6;
    u16x8 ov;
#pragma unroll
    for (int j = 0; j < 8; ++j) ov[j] = f2bf(tile[kg * 8 + j][n]);
    *(u16x8*)&Wt[(size_t)(tn * 64 + n) * K + tk * 64 + kg * 8] = ov;
  }
}

// ------------------------------------------------------------- mask scan (1 block)
__global__ __launch_bounds__(256) void k_scan(
    const int* __restrict__ mask, int* __restrict__ cpos,
    int* __restrict__ cidx, int* __restrict__ cnt) {
  const int tid = threadIdx.x;
  const int lane = tid & 63, wid = tid >> 6;
  int m[8];
  int s = 0;
#pragma unroll
  for (int j = 0; j < 8; ++j) { m[j] = mask[tid * 8 + j]; s += m[j]; }
  int ps = s;
#pragma unroll
  for (int o = 1; o < 64; o <<= 1) {
    int t = __shfl_up(ps, o);
    if (lane >= o) ps += t;
  }
  __shared__ int wsum[4];
  if (lane == 63) wsum[wid] = ps;
  __syncthreads();
  int base = 0;
  for (int w = 0; w < wid; ++w) base += wsum[w];
  int run = base + ps - s;
#pragma unroll
  for (int j = 0; j < 8; ++j) {
    int row = tid * 8 + j;
    cpos[row] = run;
    if (m[j]) cidx[run] = row;
    run += m[j];
  }
  if (tid == 255) cnt[0] = run;
}

// ------------------------------------------------------------- RMS helpers
__device__ __forceinline__ float block_sum256(float v, float* red) {
  const int tid = threadIdx.x;
#pragma unroll
  for (int o = 32; o; o >>= 1) v += __shfl_xor(v, o);
  if ((tid & 63) == 0) red[tid >> 6] = v;
  __syncthreads();
  float r = red[0] + red[1] + red[2] + red[3];
  __syncthreads();
  return r;
}

// input norm (row-masked weight select) -- used once for layer 0
__global__ __launch_bounds__(256) void k_rms(
    const float* __restrict__ h, const float* __restrict__ wt, const float* __restrict__ wa,
    const int* __restrict__ mask, u16* __restrict__ out1) {
  const int row = blockIdx.x;
  const int tid = threadIdx.x;
  const float* hr = h + (size_t)row * 2048;
  float4 v0 = ((const float4*)hr)[tid * 2];
  float4 v1 = ((const float4*)hr)[tid * 2 + 1];
  const float* f0 = (const float*)&v0;
  const float* f1 = (const float*)&v1;
  float ss = 0.f;
#pragma unroll
  for (int j = 0; j < 4; ++j) ss += f0[j] * f0[j] + f1[j] * f1[j];
  __shared__ float red[4];
  ss = block_sum256(ss, red);
  const float inv = rsqrtf(ss * (1.0f / 2048.0f) + 1e-5f);
  const int c0 = tid * 8;
  const float* w = mask[row] ? wa : wt;
  u16x8 a;
#pragma unroll
  for (int j = 0; j < 8; ++j) {
    float hv = (j < 4 ? f0[j] : f1[j - 4]) * inv;
    a[j] = f2bf(hv * w[c0 + j]);
  }
  *(u16x8*)&out1[(size_t)row * 2048 + c0] = a;
}

// fused: h += sum4 o-proj partials ; post-norm -> x (text) + compacted xc (audio)
__global__ __launch_bounds__(256) void k_redrms_post(
    float* __restrict__ h, const float* __restrict__ Pp,
    const float* __restrict__ wt, const float* __restrict__ wa,
    const int* __restrict__ mask, u16* __restrict__ x, u16* __restrict__ xc,
    const int* __restrict__ cpos) {
  const int row = blockIdx.x, tid = threadIdx.x;
  const int c0 = tid * 8;
  const size_t base = (size_t)row * 2048 + c0;
  float4 a0 = *(const float4*)&h[base];
  float4 a1 = *(const float4*)&h[base + 4];
#pragma unroll
  for (int k = 0; k < 4; ++k) {
    const float* pk = Pp + (size_t)k * 2048 * 2048;
    float4 p0 = *(const float4*)&pk[base];
    float4 p1 = *(const float4*)&pk[base + 4];
    a0.x += p0.x; a0.y += p0.y; a0.z += p0.z; a0.w += p0.w;
    a1.x += p1.x; a1.y += p1.y; a1.z += p1.z; a1.w += p1.w;
  }
  *(float4*)&h[base] = a0;
  *(float4*)&h[base + 4] = a1;
  const float* f0 = (const float*)&a0;
  const float* f1 = (const float*)&a1;
  float ss = 0.f;
#pragma unroll
  for (int j = 0; j < 4; ++j) ss += f0[j] * f0[j] + f1[j] * f1[j];
  __shared__ float red[4];
  ss = block_sum256(ss, red);
  const float inv = rsqrtf(ss * (1.0f / 2048.0f) + 1e-5f);
  u16x8 xv;
#pragma unroll
  for (int j = 0; j < 8; ++j) {
    float hv = (j < 4 ? f0[j] : f1[j - 4]) * inv;
    xv[j] = f2bf(hv * wt[c0 + j]);
  }
  *(u16x8*)&x[base] = xv;
  if (mask[row]) {
    u16x8 av;
#pragma unroll
    for (int j = 0; j < 8; ++j) {
      float hv = (j < 4 ? f0[j] : f1[j - 4]) * inv;
      av[j] = f2bf(hv * wa[c0 + j]);
    }
    *(u16x8*)&xc[(size_t)cpos[row] * 2048 + c0] = av;
  }
}

// fused: h += (text? sum4 proj partials : sum8 audio-proj partials via cpos) ;
//        then next input-norm (select) -> x, or final ln_f -> outf
__global__ __launch_bounds__(256) void k_redrms_ffn(
    float* __restrict__ h, const float* __restrict__ Psk, const float* __restrict__ Pap,
    const float* __restrict__ wt, const float* __restrict__ wa,
    const float* __restrict__ wf, const int* __restrict__ mask,
    const int* __restrict__ cpos, u16* __restrict__ x, float* __restrict__ outf, int fin) {
  const int row = blockIdx.x, tid = threadIdx.x;
  const int c0 = tid * 8;
  const size_t base = (size_t)row * 2048 + c0;
  float4 a0 = *(const float4*)&h[base];
  float4 a1 = *(const float4*)&h[base + 4];
  if (mask[row] == 0) {
#pragma unroll
    for (int k = 0; k < 4; ++k) {
      const float* pk = Psk + (size_t)k * 2048 * 2048;
      float4 p0 = *(const float4*)&pk[base];
      float4 p1 = *(const float4*)&pk[base + 4];
      a0.x += p0.x; a0.y += p0.y; a0.z += p0.z; a0.w += p0.w;
      a1.x += p1.x; a1.y += p1.y; a1.z += p1.z; a1.w += p1.w;
    }
  } else {
    const size_t cb = (size_t)cpos[row] * 2048 + c0;
#pragma unroll
    for (int k = 0; k < 8; ++k) {
      const float* pk = Pap + (size_t)k * 256 * 2048;
      float4 p0 = *(const float4*)&pk[cb];
      float4 p1 = *(const float4*)&pk[cb + 4];
      a0.x += p0.x; a0.y += p0.y; a0.z += p0.z; a0.w += p0.w;
      a1.x += p1.x; a1.y += p1.y; a1.z += p1.z; a1.w += p1.w;
    }
  }
  if (!fin) {
    *(float4*)&h[base] = a0;
    *(float4*)&h[base + 4] = a1;
  }
  const float* f0 = (const float*)&a0;
  const float* f1 = (const float*)&a1;
  float ss = 0.f;
#pragma unroll
  for (int j = 0; j < 4; ++j) ss += f0[j] * f0[j] + f1[j] * f1[j];
  __shared__ float red[4];
  ss = block_sum256(ss, red);
  const float inv = rsqrtf(ss * (1.0f / 2048.0f) + 1e-5f);
  if (fin) {
    float4 o0, o1;
    float* p0 = (float*)&o0;
    float* p1 = (float*)&o1;
#pragma unroll
    for (int j = 0; j < 4; ++j) {
      p0[j] = f0[j] * inv * wf[c0 + j];
      p1[j] = f1[j] * inv * wf[c0 + 4 + j];
    }
    *(float4*)&outf[base] = o0;
    *(float4*)&outf[base + 4] = o1;
  } else {
    const float* w = mask[row] ? wa : wt;
    u16x8 xv;
#pragma unroll
    for (int j = 0; j < 8; ++j) {
      float hv = (j < 4 ? f0[j] : f1[j - 4]) * inv;
      xv[j] = f2bf(hv * w[c0 + j]);
    }
    *(u16x8*)&x[base] = xv;
  }
}

// ------------------------------------------------------------- embedding
__global__ __launch_bounds__(256) void k_embed(
    const int* __restrict__ ids, const float* __restrict__ vocab,
    const float* __restrict__ audio, float* __restrict__ h, int* __restrict__ mask) {
  const int t = blockIdx.x;
  const int tid = threadIdx.x;
  const int id = ids[t];
  const int am = (id > 31999) ? 1 : 0;
  if (tid == 0) mask[t] = am;
  float* hr = h + (size_t)t * 2048;
  if (!am) {
    const float4* src = (const float4*)(vocab + (size_t)id * 2048);
    for (int j = tid; j < 512; j += 256) ((float4*)hr)[j] = src[j];
  } else {
    const int aid = id - 32000;
    for (int j = tid; j < 512; j += 256) {
      float4 s = {0.f, 0.f, 0.f, 0.f};
#pragma unroll
      for (int c = 0; c < 8; ++c) {
        float4 a = ((const float4*)(audio + (size_t)(aid + c * 1026) * 2048))[j];
        s.x += a.x; s.y += a.y; s.z += a.z; s.w += a.w;
      }
      ((float4*)hr)[j] = s;
    }
  }
}

// ------------------------------------------------------------- host launch
extern "C" void kernel_launch(void* const* d_in, const int* in_sizes, int n_in,
                              void* d_out, int out_size, void* d_ws, size_t ws_size,
                              hipStream_t stream) {
  const int* ids = (const int*)d_in[0];
  const float* vocab = (const float*)d_in[1];
  const float* audio = (const float*)d_in[2];
  const float* ln_in = (const float*)d_in[3];
  const float* ln_audio_in = (const float*)d_in[4];
  const float* ln_post = (const float*)d_in[5];
  const float* ln_audio_post = (const float*)d_in[6];
  const float* w_qkv = (const float*)d_in[7];
  const float* w_o = (const float*)d_in[8];
  const float* w_fc = (const float*)d_in[9];
  const float* w_proj = (const float*)d_in[10];
  const float* w_afc = (const float*)d_in[11];
  const float* w_aproj = (const float*)d_in[12];
  const float* ln_f = (const float*)d_in[13];
  float* out = (float*)d_out;

  char* p = (char*)d_ws;
  auto alloc = [&](size_t bytes) {
    char* r = p;
    p += (bytes + 255) & ~(size_t)255;
    return r;
  };
  float* h   = (float*)alloc((size_t)2048 * 2048 * 4);
  u16* x     = (u16*)alloc((size_t)2048 * 2048 * 2);
  u16* xc    = (u16*)alloc((size_t)2048 * 2048 * 2);
  u16* o     = (u16*)alloc((size_t)2048 * 2048 * 2);
  int* mask  = (int*)alloc((size_t)2048 * 4);
  int* cpos  = (int*)alloc((size_t)2048 * 4);
  int* cidx  = (int*)alloc((size_t)2048 * 4);
  int* cnt   = (int*)alloc((size_t)64 * 4);
  u16* Wt    = (u16*)alloc((size_t)8192 * 2048 * 2);
  u16* Q     = (u16*)alloc((size_t)2 * 16 * 1024 * 128 * 2);
  u16* Kb    = (u16*)alloc((size_t)2 * 8 * 1024 * 128 * 2);
  u16* VT    = (u16*)alloc((size_t)2 * 8 * 1024 * 128 * 2);
  char* A    = alloc((size_t)32 * 1024 * 1024 * 4);          // 134 MB multi-use region
  u16* P     = (u16*)alloc((size_t)32 * 1024 * 1024 * 2);    // 67 MB attn probs
  u16* t1    = (u16*)alloc((size_t)2048 * 8192 * 2);
  // Region A aliases (lifetimes disjoint in stream order):
  float* Pq    = (float*)A;                          // [2][2048][4096] qkv partials
  u16*   Sb    = (u16*)A;                            // [32][1024][1024] bf16 scores
  float* Psk   = (float*)A;                          // [4][2048][2048] o/proj partials
  float* Pafc  = (float*)(A + (size_t)67108864 + 4194304);   // [4][256][8192]
  float* Paprj = (float*)(A + (size_t)100663296 + 8388608);  // [8][256][2048]
  (void)ws_size; (void)in_sizes; (void)n_in; (void)out_size;

  k_embed<<<2048, 256, 0, stream>>>(ids, vocab, audio, h, mask);
  k_scan<<<1, 256, 0, stream>>>(mask, cpos, cidx, cnt);
  // layer-0 input norm
  k_rms<<<2048, 256, 0, stream>>>(h, ln_in, ln_audio_in, mask, x);

  for (int l = 0; l < 2; ++l) {
    // qkv: 8-phase split-K x2 -> partials -> scatter reduce
    k_transpose<<<(2048 / 64) * (4096 / 64), 256, 0, stream>>>(
        w_qkv + (size_t)l * 2048 * 4096, Wt, 2048, 4096);
    k_gemm8_qkv<<<256, 512, 0, stream>>>(x, Wt, Pq);
    k_red_qkv<<<dim3(4, 2048), 256, 0, stream>>>(Pq, Q, Kb, VT);
    // attention (bf16 scores)
    k_scores<<<dim3(36, 32), 256, 0, stream>>>(Q, Kb, Sb);
    k_softmax<<<dim3(1024, 32), 256, 0, stream>>>(Sb, P);
    k_pv<<<dim3(8, 32), 256, 0, stream>>>(P, VT, o);
    // o-proj split-K x4 -> fused reduce + residual + post-norm
    k_transpose<<<(2048 / 64) * (2048 / 64), 256, 0, stream>>>(
        w_o + (size_t)l * 2048 * 2048, Wt, 2048, 2048);
    k_gemm8_sk<<<256, 512, 0, stream>>>(o, 2048, Wt, 2048, 8, 512, Psk);
    k_redrms_post<<<2048, 256, 0, stream>>>(h, Psk, ln_post + l * 2048,
                                            ln_audio_post + l * 2048, mask, x, xc, cpos);
    // text FFN
    k_transpose<<<(2048 / 64) * (8192 / 64), 256, 0, stream>>>(
        w_fc + (size_t)l * 2048 * 8192, Wt, 2048, 8192);
    k_gemm8_fc<<<256, 512, 0, stream>>>(x, Wt, t1);
    k_transpose<<<(8192 / 64) * (2048 / 64), 256, 0, stream>>>(
        w_proj + (size_t)l * 8192 * 2048, Wt, 8192, 2048);
    k_gemm8_sk<<<256, 512, 0, stream>>>(t1, 8192, Wt, 8192, 32, 2048, Psk);
    // audio FFN (compacted, split-K 128^2 core)
    k_transpose<<<(2048 / 64) * (8192 / 64), 256, 0, stream>>>(
        w_afc + (size_t)l * 2048 * 8192, Wt, 2048, 8192);
    k_gemm_cs<<<dim3(64 * 4, 2), 256, 0, stream>>>(xc, 2048, Wt, 2048, 8, 64, Pafc, cnt);
    k_red4_silu<<<dim3(8, 256), 256, 0, stream>>>(Pafc, t1, cnt);
    k_transpose<<<(8192 / 64) * (2048 / 64), 256, 0, stream>>>(
        w_aproj + (size_t)l * 8192 * 2048, Wt, 8192, 2048);
    k_gemm_cs<<<dim3(16 * 8, 2), 256, 0, stream>>>(t1, 8192, Wt, 8192, 16, 16, Paprj, cnt);
    // fused: both-path residual add + (next input-norm | final ln_f)
    if (l == 0)
      k_redrms_ffn<<<2048, 256, 0, stream>>>(h, Psk, Paprj, ln_in + 2048,
                                             ln_audio_in + 2048, nullptr, mask, cpos, x,
                                             nullptr, 0);
    else
      k_redrms_ffn<<<2048, 256, 0, stream>>>(h, Psk, Paprj, nullptr, nullptr, ln_f, mask,
                                             cpos, nullptr, out, 1);
  }
}